// Round 5
// baseline (659.454 us; speedup 1.0000x reference)
//
#include <hip/hip_runtime.h>
#include <hip/hip_bf16.h>
#include <math.h>

// SparseAttention: B=8, N=2048, C=768, k=1638.
// Split-precision bf16 MFMA pipeline:
//   split: x->(xh,xl), W->(Wh,Wl)
//   projQK (merged): [M,1536] hi/lo planes QKh/QKl (Q=cols 0-767, K=768-1535)
//   projV: Vt transposed bf16 [B][C][N]
//   per half: QK^T (3-seg f32 logits) -> radix-select+softmax -> Pb (bf16)
//   PV: one z=8 launch (Pb1 | Pb2 pointer split), out f32
// GEMM core: 256x256 tile, 8 waves (2x4), BK=32, ring-4 LDS (128 KB),
// per-phase counted vmcnt(8) with 3-tile lookahead (T3/T4), setprio (T5).
// 64-B LDS rows -> bank-parity balanced, no swizzle needed.

#define BM 256
#define BN 256
#define BK 32
#define RD 4
#define NTHREADS 512

typedef __attribute__((ext_vector_type(8))) short bf16x8;
typedef __attribute__((ext_vector_type(4))) float f32x4;

__device__ __forceinline__ unsigned short f2bf(float f) {
    unsigned u = __float_as_uint(f);
    unsigned r = u + 0x7FFFu + ((u >> 16) & 1u);   // RN-even
    return (unsigned short)(r >> 16);
}
__device__ __forceinline__ float bf2f(unsigned short h) {
    return __uint_as_float(((unsigned)h) << 16);
}

__device__ __forceinline__ void async16(const void* g, void* l) {
    __builtin_amdgcn_global_load_lds(
        (const __attribute__((address_space(1))) void*)g,
        (__attribute__((address_space(3))) void*)l, 16, 0, 0);
}

struct GemmArgs {
    const unsigned short* A0; const unsigned short* A1; const unsigned short* A2;
    const unsigned short* B0; const unsigned short* B1; const unsigned short* B2;
    const unsigned short* A0b;  // alt A base for z >= zsplit (PV second half)
    int zsplit;                 // 0 = off
    int nseg;
    int lda, ldb;               // row strides (elements); A=[M,K], B=[N,K] (NT)
    long batchA, batchB;        // per-z element strides
    int K;                      // per-segment K (multiple of 32)
    float alpha;
};

// EPI: 0 = f32 store (alpha) | 1 = split bf16 (hi,lo) | 2 = transposed bf16 V
template <int EPI>
__global__ __launch_bounds__(NTHREADS) void gemm_bf16(
    GemmArgs g, void* Cp0, void* Cp1, int ldc, long batchC)
{
    // ring-4 K-tile buffers: 4 x (A 16KB + B 16KB) = 128 KB
    __shared__ unsigned short As[RD][BM * BK];
    __shared__ unsigned short Bs[RD][BM * BK];

    const int t    = threadIdx.x;
    const int wid  = t >> 6, lane = t & 63;
    const int wr   = wid >> 2, wc = wid & 3;     // 2 x 4 wave grid
    const int fr   = lane & 15, fq = lane >> 4;
    const int m0   = blockIdx.y * BM, n0 = blockIdx.x * BN;
    const int z    = blockIdx.z;

    // A-base select (PV reads Pb1 for z<zsplit, Pb2 re-based otherwise)
    const unsigned short* gA0 = g.A0;
    long zA = (long)z * g.batchA;
    if (g.zsplit && z >= g.zsplit) { gA0 = g.A0b; zA = (long)(z - g.zsplit) * g.batchA; }
    const long zB = (long)z * g.batchB;

    const unsigned short* Aseg[3] = { gA0, g.A1, g.A2 };
    const unsigned short* Bseg[3] = { g.B0, g.B1, g.B2 };

    // staging: thread t covers row = t/4 (+128), k-slot = (t&3)*8 elems.
    // LDS dest (wave-uniform base + lane*16): wid*1024 + r*8192  -> linear.
    const long aoff = (long)(t >> 2) * g.lda + (t & 3) * 8;
    const long boff = (long)(t >> 2) * g.ldb + (t & 3) * 8;

    f32x4 acc[8][4];
#pragma unroll
    for (int m = 0; m < 8; ++m)
#pragma unroll
        for (int n = 0; n < 4; ++n) acc[m][n] = (f32x4)0.f;

    const int tps = g.K / BK;
    const int nt  = g.nseg * tps;

    // staging cursor (tile skt is the next to stage; clamped at the end)
    int skt = 0, sseg = 0, sk0 = 0;
    const unsigned short* sA = Aseg[0] + zA + (long)m0 * g.lda;
    const unsigned short* sB = Bseg[0] + zB + (long)n0 * g.ldb;

    auto STAGE = [&](int u) {
        char* la = (char*)&As[u][0] + wid * 1024;
        char* lb = (char*)&Bs[u][0] + wid * 1024;
        const unsigned short* pa = sA + sk0 + aoff;
        const unsigned short* pb = sB + sk0 + boff;
        async16(pa,                  la);
        async16(pa + 128 * g.lda,    la + 8192);
        async16(pb,                  lb);
        async16(pb + 128 * g.ldb,    lb + 8192);
    };
    auto ADV = [&]() {
        if (skt + 1 < nt) {
            ++skt; sk0 += BK;
            if (sk0 == g.K) {
                sk0 = 0; ++sseg;
                sA = Aseg[sseg] + zA + (long)m0 * g.lda;
                sB = Bseg[sseg] + zB + (long)n0 * g.ldb;
            }
        }
    };

    // prologue: 3-tile lookahead (12 loads in flight)
    STAGE(0); ADV();
    STAGE(1); ADV();
    STAGE(2); ADV();

    for (int tt = 0; tt < nt; ++tt) {
        // stage tile tt+3 into ring unit (tt+3)&3 (freed by tt-1's end barrier)
        STAGE((tt + 3) & 3); ADV();
        // counted wait: leaves tiles tt+2, tt+3 (8 loads) in flight; forces
        // tile tt (issued 3 iterations ago) fully landed for THIS wave; the
        // barrier then publishes all waves' contributions.
        asm volatile("s_waitcnt vmcnt(8)" ::: "memory");
        __builtin_amdgcn_sched_barrier(0);
        __builtin_amdgcn_s_barrier();
        __builtin_amdgcn_sched_barrier(0);

        const unsigned short* Ab = &As[tt & 3][0];
        const unsigned short* Bb = &Bs[tt & 3][0];

        bf16x8 bfr[4];
#pragma unroll
        for (int n = 0; n < 4; ++n)
            bfr[n] = *(const bf16x8*)&Bb[(wc * 64 + n * 16 + fr) * BK + fq * 8];
        bf16x8 afr[8];
#pragma unroll
        for (int m = 0; m < 8; ++m)
            afr[m] = *(const bf16x8*)&Ab[(wr * 128 + m * 16 + fr) * BK + fq * 8];

        __builtin_amdgcn_s_setprio(1);
#pragma unroll
        for (int m = 0; m < 8; ++m)
#pragma unroll
            for (int n = 0; n < 4; ++n)
                acc[m][n] = __builtin_amdgcn_mfma_f32_16x16x32_bf16(
                    afr[m], bfr[n], acc[m][n], 0, 0, 0);
        __builtin_amdgcn_s_setprio(0);

        __builtin_amdgcn_sched_barrier(0);
        __builtin_amdgcn_s_barrier();   // unit tt&3 free for restage at tt+1
        __builtin_amdgcn_sched_barrier(0);
    }

    // ---- epilogue: C/D layout col = lane&15, row = (lane>>4)*4 + j ----
#pragma unroll
    for (int m = 0; m < 8; ++m) {
        const int gr0 = m0 + wr * 128 + m * 16 + fq * 4;
#pragma unroll
        for (int n = 0; n < 4; ++n) {
            const int gc = n0 + wc * 64 + n * 16 + fr;
            if (EPI == 0) {
                float* Cf = (float*)Cp0 + (long)z * batchC;
#pragma unroll
                for (int j = 0; j < 4; ++j)
                    Cf[(long)(gr0 + j) * ldc + gc] = g.alpha * acc[m][n][j];
            } else if (EPI == 1) {
                unsigned short* H = (unsigned short*)Cp0;
                unsigned short* L = (unsigned short*)Cp1;
#pragma unroll
                for (int j = 0; j < 4; ++j) {
                    const float v = acc[m][n][j];
                    const unsigned short h = f2bf(v);
                    H[(long)(gr0 + j) * ldc + gc] = h;
                    L[(long)(gr0 + j) * ldc + gc] = f2bf(v - bf2f(h));
                }
            } else {
                unsigned short* Vt = (unsigned short*)Cp0;
                ushort4 p;
                p.x = f2bf(acc[m][n][0]); p.y = f2bf(acc[m][n][1]);
                p.z = f2bf(acc[m][n][2]); p.w = f2bf(acc[m][n][3]);
                const long idx = ((long)(gr0 >> 11) * 768 + gc) * 2048 + (gr0 & 2047);
                *(ushort4*)&Vt[idx] = p;
            }
        }
    }
}

// --------------------------- conversion: f32 -> (hi, lo) bf16 planes -------
__global__ __launch_bounds__(256) void split_f32(
    const float* __restrict__ in, unsigned short* __restrict__ hi,
    unsigned short* __restrict__ lo, int n4)
{
    const int i = blockIdx.x * 256 + threadIdx.x;
    if (i >= n4) return;
    const float4 v = ((const float4*)in)[i];
    ushort4 h, l;
    h.x = f2bf(v.x); l.x = f2bf(v.x - bf2f(h.x));
    h.y = f2bf(v.y); l.y = f2bf(v.y - bf2f(h.y));
    h.z = f2bf(v.z); l.z = f2bf(v.z - bf2f(h.z));
    h.w = f2bf(v.w); l.w = f2bf(v.w - bf2f(h.w));
    ((ushort4*)hi)[i] = h;
    ((ushort4*)lo)[i] = l;
}

// ------------------------------------------------- top-k + softmax ---------
#define ROWN 2048

__device__ __forceinline__ unsigned fkey(float f) {
    unsigned b = __float_as_uint(f);
    return b ^ ((b & 0x80000000u) ? 0xFFFFFFFFu : 0x80000000u);
}

__global__ __launch_bounds__(256) void topk_softmax_rows(
    const float* __restrict__ S, unsigned short* __restrict__ P, int kkeep)
{
    __shared__ float    sv[ROWN];
    __shared__ unsigned hist[256];
    __shared__ unsigned cum[257];
    __shared__ float    red[256];
    __shared__ unsigned sel_prefix;
    __shared__ unsigned sel_kr;

    const float* row = S + (long)blockIdx.x * ROWN;
    unsigned short* prow = P + (long)blockIdx.x * ROWN;
    const int t = threadIdx.x;

#pragma unroll
    for (int r = 0; r < 2; ++r)
        *reinterpret_cast<float4*>(&sv[t * 4 + r * 1024]) =
            *reinterpret_cast<const float4*>(&row[t * 4 + r * 1024]);
    if (t == 0) { sel_prefix = 0u; sel_kr = (unsigned)kkeep; }
    __syncthreads();

    float m = -3.4e38f;
#pragma unroll
    for (int j = 0; j < 8; ++j) m = fmaxf(m, sv[t + 256 * j]);
    red[t] = m;
    __syncthreads();
    for (int s = 128; s > 0; s >>= 1) {
        if (t < s) red[t] = fmaxf(red[t], red[t + s]);
        __syncthreads();
    }
    const float smax = red[0];
    __syncthreads();

    // radix-select, 3 passes (24-bit threshold; superset of true top-k,
    // expected extras ~0.02/row given order-stat gaps >> 2^-15 quantum)
    for (int p = 3; p >= 1; --p) {
        hist[t] = 0u;
        __syncthreads();
        const unsigned pref = sel_prefix;
        const unsigned kr   = sel_kr;
        const int sh = 8 * p;
        const unsigned himask = ~(((1u << sh) << 8) - 1u);
#pragma unroll
        for (int j = 0; j < 8; ++j) {
            const unsigned u = fkey(sv[t + 256 * j]);
            if (((u ^ pref) & himask) == 0u)
                atomicAdd(&hist[(u >> sh) & 255u], 1u);
        }
        __syncthreads();
        cum[t] = hist[t];
        if (t == 0) cum[256] = 0u;
        __syncthreads();
        for (int s = 1; s < 256; s <<= 1) {
            const unsigned add = (t + s < 256) ? cum[t + s] : 0u;
            __syncthreads();
            cum[t] += add;
            __syncthreads();
        }
        if (cum[t] >= kr && cum[t + 1] < kr) {
            sel_prefix = pref | ((unsigned)t << sh);
            sel_kr     = kr - cum[t + 1];
        }
        __syncthreads();
    }
    const unsigned tu = sel_prefix;

    float s = 0.f;
#pragma unroll
    for (int j = 0; j < 8; ++j) {
        const int i   = t + 256 * j;
        const float x = sv[i];
        const float e = (fkey(x) >= tu) ? __expf(x - smax) : 0.f;
        sv[i] = e;
        s += e;
    }
    red[t] = s;
    __syncthreads();
    for (int st = 128; st > 0; st >>= 1) {
        if (t < st) red[t] += red[t + st];
        __syncthreads();
    }
    const float inv = 1.0f / red[0];
    __syncthreads();

#pragma unroll
    for (int r = 0; r < 2; ++r) {
        const float4 v = *reinterpret_cast<const float4*>(&sv[t * 4 + r * 1024]);
        ushort4 o;
        o.x = f2bf(v.x * inv); o.y = f2bf(v.y * inv);
        o.z = f2bf(v.z * inv); o.w = f2bf(v.w * inv);
        *(ushort4*)&prow[t * 4 + r * 1024] = o;
    }
}

// ---------------------------------------------------------------- launch ---
extern "C" void kernel_launch(void* const* d_in, const int* in_sizes, int n_in,
                              void* d_out, int out_size, void* d_ws, size_t ws_size,
                              hipStream_t stream)
{
    const float* x = (const float*)d_in[0];
    const float* W = (const float*)d_in[1];   // [3C, C]
    float* out = (float*)d_out;

    const int B = 8, N = 2048, C = 768;
    const int M = B * N;                      // 16384
    const int kkeep = 1638;

    char* ws = (char*)d_ws;
    // layout (bytes): QKh 50.33M | QKl 50.33M | Vt 25.17M | S 67.11M | Pb1 33.55M
    unsigned short* QKh = (unsigned short*)(ws);
    unsigned short* QKl = (unsigned short*)(ws + 50331648);
    unsigned short* Vt  = (unsigned short*)(ws + 100663296);
    float*          S   = (float*)(ws + 125829120);
    unsigned short* Pb1 = (unsigned short*)(ws + 192937984);
    // aliases: xh/xl live in S region (dead before S written); W planes in Pb1
    // region (dead before topk1); Pb2 in QKh region (dead after QK2).
    unsigned short* xh  = (unsigned short*)(ws + 125829120);
    unsigned short* xl  = (unsigned short*)(ws + 125829120 + 25165824);
    unsigned short* Wh  = (unsigned short*)(ws + 192937984);
    unsigned short* Wl  = (unsigned short*)(ws + 192937984 + 3538944);
    unsigned short* Pb2 = (unsigned short*)(ws);

    split_f32<<<dim3((M * C / 4) / 256), 256, 0, stream>>>(x, xh, xl, M * C / 4);
    split_f32<<<dim3((3 * C * C / 4) / 256), 256, 0, stream>>>(W, Wh, Wl, 3 * C * C / 4);

    // ---- merged Q+K projection: [M,768] x [1536,768]^T -> QKh/QKl [M,1536] ----
    {
        GemmArgs pa{};
        pa.nseg = 3; pa.lda = C; pa.ldb = C; pa.batchA = 0; pa.batchB = 0;
        pa.K = C; pa.alpha = 1.f; pa.zsplit = 0;
        pa.A0 = xh; pa.A1 = xh; pa.A2 = xl;
        pa.B0 = Wh; pa.B1 = Wl; pa.B2 = Wh;
        gemm_bf16<1><<<dim3(1536 / BN, M / BM, 1), NTHREADS, 0, stream>>>(
            pa, QKh, QKl, 1536, 0);
    }
    // ---- V projection -> Vt [B][C][N] ----
    {
        GemmArgs pv{};
        pv.nseg = 1; pv.lda = C; pv.ldb = C; pv.batchA = 0; pv.batchB = 0;
        pv.K = C; pv.alpha = 1.f; pv.zsplit = 0;
        pv.A0 = xh; pv.B0 = Wh + (size_t)1536 * C;
        gemm_bf16<2><<<dim3(C / BN, M / BM, 1), NTHREADS, 0, stream>>>(
            pv, Vt, nullptr, 0, 0);
    }
    // ---- per half: QK^T -> topk/softmax ----
    for (int h = 0; h < 2; ++h) {
        const size_t ho = (size_t)h * 4 * N * 1536;  // row offset into QK planes
        GemmArgs qk{};
        qk.nseg = 3; qk.lda = 1536; qk.ldb = 1536;
        qk.batchA = (long)N * 1536; qk.batchB = (long)N * 1536; qk.K = C;
        qk.alpha = 1.0f / sqrtf((float)C); qk.zsplit = 0;
        qk.A0 = QKh + ho; qk.A1 = QKh + ho; qk.A2 = QKl + ho;
        qk.B0 = QKh + ho + C; qk.B1 = QKl + ho + C; qk.B2 = QKh + ho + C;
        gemm_bf16<0><<<dim3(N / BN, N / BM, 4), NTHREADS, 0, stream>>>(
            qk, S, nullptr, N, (long)N * N);

        topk_softmax_rows<<<dim3(4 * N), 256, 0, stream>>>(
            S, h == 0 ? Pb1 : Pb2, kkeep);
    }
    // ---- PV: one z=8 launch (z<4 -> Pb1, z>=4 -> Pb2) ----
    {
        GemmArgs pvv{};
        pvv.nseg = 1; pvv.lda = N; pvv.ldb = N;
        pvv.batchA = (long)N * N; pvv.batchB = (long)C * N; pvv.K = N;
        pvv.alpha = 1.f;
        pvv.A0 = Pb1; pvv.A0b = Pb2; pvv.zsplit = 4;
        pvv.B0 = Vt;
        gemm_bf16<0><<<dim3(C / BN, N / BM, 8), NTHREADS, 0, stream>>>(
            pvv, out, nullptr, C, (long)N * C);
    }
}

// Round 6
// 560.254 us; speedup vs baseline: 1.1771x; 1.1771x over previous
//
#include <hip/hip_runtime.h>
#include <hip/hip_bf16.h>
#include <math.h>

// SparseAttention: B=8, N=2048, C=768, k=1638.
// Split-precision bf16 MFMA pipeline:
//   split: x->(xh,xl), W->(Wh,Wl)
//   projQK (merged): [M,1536] hi/lo planes QKh/QKl (Q=cols 0-767, K=768-1535)
//   projV: Vt transposed bf16 [B][C][N]
//   per half: QK^T (3-seg f32 logits) -> radix-select+softmax -> Pb (bf16)
//   PV: one z=8 launch (Pb1 | Pb2 pointer split), out f32
// GEMM core (m201-style 8-phase): 256x256 tile, 8 waves (2x4), BK=64,
// 2 K-tile LDS buffers (128 KB), XOR-swizzled rows (proven r4, 0 conflicts),
// 4 phases/K-tile {ds_read ∥ stage-group -> barrier -> lgkmcnt(0) -> 16 MFMA
// -> barrier}, staging cursor 6 groups ahead, vmcnt(4) once per K-tile.

#define BM 256
#define BN 256
#define BK 64
#define NTHREADS 512

typedef __attribute__((ext_vector_type(8))) short bf16x8;
typedef __attribute__((ext_vector_type(4))) float f32x4;

__device__ __forceinline__ unsigned short f2bf(float f) {
    unsigned u = __float_as_uint(f);
    unsigned r = u + 0x7FFFu + ((u >> 16) & 1u);   // RN-even
    return (unsigned short)(r >> 16);
}
__device__ __forceinline__ float bf2f(unsigned short h) {
    return __uint_as_float(((unsigned)h) << 16);
}

__device__ __forceinline__ void async16(const void* g, void* l) {
    __builtin_amdgcn_global_load_lds(
        (const __attribute__((address_space(1))) void*)g,
        (__attribute__((address_space(3))) void*)l, 16, 0, 0);
}

struct GemmArgs {
    const unsigned short* A0; const unsigned short* A1; const unsigned short* A2;
    const unsigned short* B0; const unsigned short* B1; const unsigned short* B2;
    const unsigned short* A0b;  // alt A base for z >= zsplit (PV second half)
    int zsplit;                 // 0 = off
    int nseg;
    int lda, ldb;               // row strides (elements); A=[M,K], B=[N,K] (NT)
    long batchA, batchB;        // per-z element strides
    int K;                      // per-segment K (multiple of 64)
    float alpha;
};

// EPI: 0 = f32 store (alpha) | 1 = split bf16 (hi,lo) | 2 = transposed bf16 V
template <int EPI>
__global__ __launch_bounds__(NTHREADS) void gemm_bf16(
    GemmArgs g, void* Cp0, void* Cp1, int ldc, long batchC)
{
    // 2 K-tile buffers: 2 x (A 32KB + B 32KB) = 128 KB.
    // Row layout: 64 k-elems = 128 B = 8 x 16B slots; global slot s of row r
    // is stored at LDS slot s ^ (r & 7) (involution; r4-proven, 0 conflicts).
    __shared__ unsigned short As[2][BM * BK];
    __shared__ unsigned short Bs[2][BM * BK];

    const int t    = threadIdx.x;
    const int wid  = t >> 6, lane = t & 63;
    const int wr   = wid >> 2, wc = wid & 3;     // 2 x 4 wave grid
    const int fr   = lane & 15, fq = lane >> 4;
    const int m0   = blockIdx.y * BM, n0 = blockIdx.x * BN;
    const int z    = blockIdx.z;

    const unsigned short* gA0 = g.A0;
    long zA = (long)z * g.batchA;
    if (g.zsplit && z >= g.zsplit) { gA0 = g.A0b; zA = (long)(z - g.zsplit) * g.batchA; }
    const long zB = (long)z * g.batchB;

    const unsigned short* Aseg[3] = { gA0, g.A1, g.A2 };
    const unsigned short* Bseg[3] = { g.B0, g.B1, g.B2 };

    // staging geometry (r4-proven): per 64-row round, thread covers
    // row = wid*8 + (lane>>3), 16B slot (lane&7); inverse-swizzled source.
    const int srow  = wid * 8 + (lane >> 3);
    const int sgcol = ((lane & 7) ^ (lane >> 3)) * 8;

    f32x4 acc[8][4];
#pragma unroll
    for (int m = 0; m < 8; ++m)
#pragma unroll
        for (int n = 0; n < 4; ++n) acc[m][n] = (f32x4)0.f;

    const int nt = g.nseg * (g.K / BK);   // total K-tiles (>= 12 for all uses)

    // ---- staging cursor: group sg (2 loads each); tile sg>>2, part sg&3 ----
    // parts: 0 = B rows 0-127, 1 = B rows 128-255, 2 = A rows 0-127, 3 = A rows 128-255
    int sg = 0, sseg = 0, sk0 = 0;
    const unsigned short* sA = Aseg[0] + zA + (long)m0 * g.lda;
    const unsigned short* sB = Bseg[0] + zB + (long)n0 * g.ldb;

    auto STAGE_GROUP = [&]() {
        if (sg < 4 * nt) {
            const int u  = (sg >> 2) & 1;
            const int gp = sg & 3;
            if (gp < 2) {
                char* lb = (char*)&Bs[u][0] + wid * 1024 + gp * 16384;
                const unsigned short* pb = sB + sk0 + sgcol;
                async16(pb + (long)(srow + gp * 128     ) * g.ldb, lb);
                async16(pb + (long)(srow + gp * 128 + 64) * g.ldb, lb + 8192);
            } else {
                const int ap = gp - 2;
                char* la = (char*)&As[u][0] + wid * 1024 + ap * 16384;
                const unsigned short* pa = sA + sk0 + sgcol;
                async16(pa + (long)(srow + ap * 128     ) * g.lda, la);
                async16(pa + (long)(srow + ap * 128 + 64) * g.lda, la + 8192);
            }
            ++sg;
            if ((sg & 3) == 0) {          // finished a tile: advance k cursor
                sk0 += BK;
                if (sk0 == g.K && (sg >> 2) < nt) {
                    sk0 = 0; ++sseg;
                    sA = Aseg[sseg] + zA + (long)m0 * g.lda;
                    sB = Bseg[sseg] + zB + (long)n0 * g.ldb;
                }
            }
        }
    };

    // prologue: 6 groups ahead (tile0 fully, tile1 B-halves); publish tile0
    STAGE_GROUP(); STAGE_GROUP(); STAGE_GROUP();
    STAGE_GROUP(); STAGE_GROUP(); STAGE_GROUP();
    asm volatile("s_waitcnt vmcnt(4)" ::: "memory");
    __builtin_amdgcn_sched_barrier(0);
    __builtin_amdgcn_s_barrier();
    __builtin_amdgcn_sched_barrier(0);

    bf16x8 fA[4][2], fB[4][2];

    for (int tt = 0; tt < nt; ++tt) {
        const unsigned short* Ab = &As[tt & 1][0];
        const unsigned short* Bb = &Bs[tt & 1][0];

        auto LDA4 = [&](int mbase) {      // read A frags mbase..mbase+3 (both ks)
#pragma unroll
            for (int mi = 0; mi < 4; ++mi) {
                const int rr = wr * 128 + (mbase + mi) * 16 + fr;
                fA[mi][0] = *(const bf16x8*)&Ab[rr * 64 + ((fq    ) ^ (rr & 7)) * 8];
                fA[mi][1] = *(const bf16x8*)&Ab[rr * 64 + ((fq + 4) ^ (rr & 7)) * 8];
            }
        };
        auto LDB2 = [&](int nbase) {      // read B frags nbase..nbase+1 (both ks)
#pragma unroll
            for (int ni = 0; ni < 2; ++ni) {
                const int rr = wc * 64 + (nbase + ni) * 16 + fr;
                fB[nbase + ni][0] = *(const bf16x8*)&Bb[rr * 64 + ((fq    ) ^ (rr & 7)) * 8];
                fB[nbase + ni][1] = *(const bf16x8*)&Bb[rr * 64 + ((fq + 4) ^ (rr & 7)) * 8];
            }
        };
        auto MFMA16 = [&](int mq, int nq) {   // quadrant: acc rows mq*4.., cols nq*2..
            __builtin_amdgcn_s_setprio(1);
#pragma unroll
            for (int mi = 0; mi < 4; ++mi)
#pragma unroll
                for (int ni = 0; ni < 2; ++ni)
#pragma unroll
                    for (int ks = 0; ks < 2; ++ks)
                        acc[mq * 4 + mi][nq * 2 + ni] =
                            __builtin_amdgcn_mfma_f32_16x16x32_bf16(
                                fA[mi][ks], fB[nq * 2 + ni][ks],
                                acc[mq * 4 + mi][nq * 2 + ni], 0, 0, 0);
            __builtin_amdgcn_s_setprio(0);
        };
        auto BAR = [&]() {
            __builtin_amdgcn_sched_barrier(0);
            __builtin_amdgcn_s_barrier();
            __builtin_amdgcn_sched_barrier(0);
        };
        auto LGKM0 = [&]() {
            asm volatile("s_waitcnt lgkmcnt(0)" ::: "memory");
            __builtin_amdgcn_sched_barrier(0);
        };

        // phase 0: read A[m0-3]+B[n0-1]; stage (tile tt+1, A rows 0-127); Q(0,0)
        LDA4(0); LDB2(0);
        STAGE_GROUP();
        BAR(); LGKM0();
        MFMA16(0, 0);
        BAR();

        // phase 1: read B[n2-3]; stage (tile tt+1, A rows 128-255); Q(0,1)
        LDB2(2);
        STAGE_GROUP();
        BAR(); LGKM0();
        MFMA16(0, 1);
        BAR();

        // phase 2: read A[m4-7]; stage (tile tt+2, B rows 0-127); Q(1,0)
        LDA4(4);
        STAGE_GROUP();
        BAR(); LGKM0();
        MFMA16(1, 0);
        BAR();

        // phase 3: stage (tile tt+2, B rows 128-255); Q(1,1); counted vmcnt
        STAGE_GROUP();
        BAR();
        MFMA16(1, 1);
        // publish tile tt+1: its 4 groups were staged >=2 phases ago; leave
        // tile tt+2's two B-groups (4 loads) in flight except near the end.
        if (tt >= nt - 2) {
            asm volatile("s_waitcnt vmcnt(0)" ::: "memory");
        } else {
            asm volatile("s_waitcnt vmcnt(4)" ::: "memory");
        }
        BAR();
    }

    // ---- epilogue: C/D layout col = lane&15, row = (lane>>4)*4 + j ----
#pragma unroll
    for (int m = 0; m < 8; ++m) {
        const int gr0 = m0 + wr * 128 + m * 16 + fq * 4;
#pragma unroll
        for (int n = 0; n < 4; ++n) {
            const int gc = n0 + wc * 64 + n * 16 + fr;
            if (EPI == 0) {
                float* Cf = (float*)Cp0 + (long)z * batchC;
#pragma unroll
                for (int j = 0; j < 4; ++j)
                    Cf[(long)(gr0 + j) * ldc + gc] = g.alpha * acc[m][n][j];
            } else if (EPI == 1) {
                unsigned short* H = (unsigned short*)Cp0;
                unsigned short* L = (unsigned short*)Cp1;
#pragma unroll
                for (int j = 0; j < 4; ++j) {
                    const float v = acc[m][n][j];
                    const unsigned short h = f2bf(v);
                    H[(long)(gr0 + j) * ldc + gc] = h;
                    L[(long)(gr0 + j) * ldc + gc] = f2bf(v - bf2f(h));
                }
            } else {
                unsigned short* Vt = (unsigned short*)Cp0;
                ushort4 p;
                p.x = f2bf(acc[m][n][0]); p.y = f2bf(acc[m][n][1]);
                p.z = f2bf(acc[m][n][2]); p.w = f2bf(acc[m][n][3]);
                const long idx = ((long)(gr0 >> 11) * 768 + gc) * 2048 + (gr0 & 2047);
                *(ushort4*)&Vt[idx] = p;
            }
        }
    }
}

// --------------------------- conversion: f32 -> (hi, lo) bf16 planes -------
__global__ __launch_bounds__(256) void split_f32(
    const float* __restrict__ in, unsigned short* __restrict__ hi,
    unsigned short* __restrict__ lo, int n4)
{
    const int i = blockIdx.x * 256 + threadIdx.x;
    if (i >= n4) return;
    const float4 v = ((const float4*)in)[i];
    ushort4 h, l;
    h.x = f2bf(v.x); l.x = f2bf(v.x - bf2f(h.x));
    h.y = f2bf(v.y); l.y = f2bf(v.y - bf2f(h.y));
    h.z = f2bf(v.z); l.z = f2bf(v.z - bf2f(h.z));
    h.w = f2bf(v.w); l.w = f2bf(v.w - bf2f(h.w));
    ((ushort4*)hi)[i] = h;
    ((ushort4*)lo)[i] = l;
}

// ------------------------------------------------- top-k + softmax ---------
#define ROWN 2048

__device__ __forceinline__ unsigned fkey(float f) {
    unsigned b = __float_as_uint(f);
    return b ^ ((b & 0x80000000u) ? 0xFFFFFFFFu : 0x80000000u);
}

__global__ __launch_bounds__(256) void topk_softmax_rows(
    const float* __restrict__ S, unsigned short* __restrict__ P, int kkeep)
{
    __shared__ float    sv[ROWN];
    __shared__ unsigned hist[256];
    __shared__ unsigned cum[257];
    __shared__ float    red[256];
    __shared__ unsigned sel_prefix;
    __shared__ unsigned sel_kr;

    const float* row = S + (long)blockIdx.x * ROWN;
    unsigned short* prow = P + (long)blockIdx.x * ROWN;
    const int t = threadIdx.x;

#pragma unroll
    for (int r = 0; r < 2; ++r)
        *reinterpret_cast<float4*>(&sv[t * 4 + r * 1024]) =
            *reinterpret_cast<const float4*>(&row[t * 4 + r * 1024]);
    if (t == 0) { sel_prefix = 0u; sel_kr = (unsigned)kkeep; }
    __syncthreads();

    float m = -3.4e38f;
#pragma unroll
    for (int j = 0; j < 8; ++j) m = fmaxf(m, sv[t + 256 * j]);
    red[t] = m;
    __syncthreads();
    for (int s = 128; s > 0; s >>= 1) {
        if (t < s) red[t] = fmaxf(red[t], red[t + s]);
        __syncthreads();
    }
    const float smax = red[0];
    __syncthreads();

    // radix-select, 3 passes (24-bit threshold; superset of true top-k,
    // expected extras ~0.02/row given order-stat gaps >> 2^-15 quantum)
    for (int p = 3; p >= 1; --p) {
        hist[t] = 0u;
        __syncthreads();
        const unsigned pref = sel_prefix;
        const unsigned kr   = sel_kr;
        const int sh = 8 * p;
        const unsigned himask = ~(((1u << sh) << 8) - 1u);
#pragma unroll
        for (int j = 0; j < 8; ++j) {
            const unsigned u = fkey(sv[t + 256 * j]);
            if (((u ^ pref) & himask) == 0u)
                atomicAdd(&hist[(u >> sh) & 255u], 1u);
        }
        __syncthreads();
        cum[t] = hist[t];
        if (t == 0) cum[256] = 0u;
        __syncthreads();
        for (int s = 1; s < 256; s <<= 1) {
            const unsigned add = (t + s < 256) ? cum[t + s] : 0u;
            __syncthreads();
            cum[t] += add;
            __syncthreads();
        }
        if (cum[t] >= kr && cum[t + 1] < kr) {
            sel_prefix = pref | ((unsigned)t << sh);
            sel_kr     = kr - cum[t + 1];
        }
        __syncthreads();
    }
    const unsigned tu = sel_prefix;

    float s = 0.f;
#pragma unroll
    for (int j = 0; j < 8; ++j) {
        const int i   = t + 256 * j;
        const float x = sv[i];
        const float e = (fkey(x) >= tu) ? __expf(x - smax) : 0.f;
        sv[i] = e;
        s += e;
    }
    red[t] = s;
    __syncthreads();
    for (int st = 128; st > 0; st >>= 1) {
        if (t < st) red[t] += red[t + st];
        __syncthreads();
    }
    const float inv = 1.0f / red[0];
    __syncthreads();

#pragma unroll
    for (int r = 0; r < 2; ++r) {
        const float4 v = *reinterpret_cast<const float4*>(&sv[t * 4 + r * 1024]);
        ushort4 o;
        o.x = f2bf(v.x * inv); o.y = f2bf(v.y * inv);
        o.z = f2bf(v.z * inv); o.w = f2bf(v.w * inv);
        *(ushort4*)&prow[t * 4 + r * 1024] = o;
    }
}

// ---------------------------------------------------------------- launch ---
extern "C" void kernel_launch(void* const* d_in, const int* in_sizes, int n_in,
                              void* d_out, int out_size, void* d_ws, size_t ws_size,
                              hipStream_t stream)
{
    const float* x = (const float*)d_in[0];
    const float* W = (const float*)d_in[1];   // [3C, C]
    float* out = (float*)d_out;

    const int B = 8, N = 2048, C = 768;
    const int M = B * N;                      // 16384
    const int kkeep = 1638;

    char* ws = (char*)d_ws;
    // layout (bytes): QKh 50.33M | QKl 50.33M | Vt 25.17M | S 67.11M | Pb1 33.55M
    unsigned short* QKh = (unsigned short*)(ws);
    unsigned short* QKl = (unsigned short*)(ws + 50331648);
    unsigned short* Vt  = (unsigned short*)(ws + 100663296);
    float*          S   = (float*)(ws + 125829120);
    unsigned short* Pb1 = (unsigned short*)(ws + 192937984);
    // aliases: xh/xl live in S region (dead before S written); W planes in Pb1
    // region (dead before topk1); Pb2 in QKh region (dead after QK2).
    unsigned short* xh  = (unsigned short*)(ws + 125829120);
    unsigned short* xl  = (unsigned short*)(ws + 125829120 + 25165824);
    unsigned short* Wh  = (unsigned short*)(ws + 192937984);
    unsigned short* Wl  = (unsigned short*)(ws + 192937984 + 3538944);
    unsigned short* Pb2 = (unsigned short*)(ws);

    split_f32<<<dim3((M * C / 4) / 256), 256, 0, stream>>>(x, xh, xl, M * C / 4);
    split_f32<<<dim3((3 * C * C / 4) / 256), 256, 0, stream>>>(W, Wh, Wl, 3 * C * C / 4);

    // ---- merged Q+K projection: [M,768] x [1536,768]^T -> QKh/QKl [M,1536] ----
    {
        GemmArgs pa{};
        pa.nseg = 3; pa.lda = C; pa.ldb = C; pa.batchA = 0; pa.batchB = 0;
        pa.K = C; pa.alpha = 1.f; pa.zsplit = 0;
        pa.A0 = xh; pa.A1 = xh; pa.A2 = xl;
        pa.B0 = Wh; pa.B1 = Wl; pa.B2 = Wh;
        gemm_bf16<1><<<dim3(1536 / BN, M / BM, 1), NTHREADS, 0, stream>>>(
            pa, QKh, QKl, 1536, 0);
    }
    // ---- V projection -> Vt [B][C][N] ----
    {
        GemmArgs pv{};
        pv.nseg = 1; pv.lda = C; pv.ldb = C; pv.batchA = 0; pv.batchB = 0;
        pv.K = C; pv.alpha = 1.f; pv.zsplit = 0;
        pv.A0 = xh; pv.B0 = Wh + (size_t)1536 * C;
        gemm_bf16<2><<<dim3(C / BN, M / BM, 1), NTHREADS, 0, stream>>>(
            pv, Vt, nullptr, 0, 0);
    }
    // ---- per half: QK^T -> topk/softmax ----
    for (int h = 0; h < 2; ++h) {
        const size_t ho = (size_t)h * 4 * N * 1536;  // row offset into QK planes
        GemmArgs qk{};
        qk.nseg = 3; qk.lda = 1536; qk.ldb = 1536;
        qk.batchA = (long)N * 1536; qk.batchB = (long)N * 1536; qk.K = C;
        qk.alpha = 1.0f / sqrtf((float)C); qk.zsplit = 0;
        qk.A0 = QKh + ho; qk.A1 = QKh + ho; qk.A2 = QKl + ho;
        qk.B0 = QKh + ho + C; qk.B1 = QKl + ho + C; qk.B2 = QKh + ho + C;
        gemm_bf16<0><<<dim3(N / BN, N / BM, 4), NTHREADS, 0, stream>>>(
            qk, S, nullptr, N, (long)N * N);

        topk_softmax_rows<<<dim3(4 * N), 256, 0, stream>>>(
            S, h == 0 ? Pb1 : Pb2, kkeep);
    }
    // ---- PV: one z=8 launch (z<4 -> Pb1, z>=4 -> Pb2) ----
    {
        GemmArgs pvv{};
        pvv.nseg = 1; pvv.lda = N; pvv.ldb = N;
        pvv.batchA = (long)N * N; pvv.batchB = (long)C * N; pvv.K = N;
        pvv.alpha = 1.f;
        pvv.A0 = Pb1; pvv.A0b = Pb2; pvv.zsplit = 4;
        pvv.B0 = Vt;
        gemm_bf16<0><<<dim3(C / BN, N / BM, 8), NTHREADS, 0, stream>>>(
            pvv, out, nullptr, C, (long)N * C);
    }
}

// Round 7
// 366.921 us; speedup vs baseline: 1.7973x; 1.5269x over previous
//
#include <hip/hip_runtime.h>
#include <hip/hip_bf16.h>
#include <math.h>

// SparseAttention: B=8, N=2048, C=768, k=1638.
// Plain-bf16 MFMA pipeline (precision analysis r7: logit err sigma ~2.7e-3 ->
// ~2 top-k boundary swaps/row, absmax ~3e-3 << 7.6e-3 threshold):
//   cast: x->xb, W->Wb (bf16)
//   projQK: QKb [M,1536] = xb @ Wqk^T     (1-seg, plain bf16 out)
//   projV:  Vt  [B][C][N] = xb @ Wv^T     (transposed bf16 out)
//   per half: S = Q K^T/sqrt(C) (f32) -> radix-select+softmax -> Pb (bf16)
//   PV: one z=8 launch (Pb1 | Pb2 pointer split), out f32
// GEMM core: unchanged r6 structure (256x256, 8 waves, BK=64, 2 K-tile LDS
// dbuf, XOR-swizzle involution (0 conflicts), 4 phases/K-tile, counted
// vmcnt(4), setprio) — proven correct r4/r6.

#define BM 256
#define BN 256
#define BK 64
#define NTHREADS 512

typedef __attribute__((ext_vector_type(8))) short bf16x8;
typedef __attribute__((ext_vector_type(4))) float f32x4;

__device__ __forceinline__ unsigned short f2bf(float f) {
    unsigned u = __float_as_uint(f);
    unsigned r = u + 0x7FFFu + ((u >> 16) & 1u);   // RN-even
    return (unsigned short)(r >> 16);
}

__device__ __forceinline__ void async16(const void* g, void* l) {
    __builtin_amdgcn_global_load_lds(
        (const __attribute__((address_space(1))) void*)g,
        (__attribute__((address_space(3))) void*)l, 16, 0, 0);
}

struct GemmArgs {
    const unsigned short* A0;
    const unsigned short* B0;
    const unsigned short* A0b;  // alt A base for z >= zsplit (PV second half)
    int zsplit;                 // 0 = off
    int lda, ldb;               // row strides (elements); A=[M,K], B=[N,K] (NT)
    long batchA, batchB;        // per-z element strides
    int K;                      // multiple of 64
    float alpha;
};

// EPI: 0 = f32 store (alpha) | 2 = transposed bf16 V | 3 = plain bf16
template <int EPI>
__global__ __launch_bounds__(NTHREADS) void gemm_bf16(
    GemmArgs g, void* Cp0, int ldc, long batchC)
{
    // 2 K-tile buffers: 2 x (A 32KB + B 32KB) = 128 KB.
    // Row = 64 k-elems = 128 B = 8 x 16B slots; global slot s of row r stored
    // at LDS slot s ^ (r & 7) (involution; r4/r6-proven, 0 bank conflicts).
    __shared__ unsigned short As[2][BM * BK];
    __shared__ unsigned short Bs[2][BM * BK];

    const int t    = threadIdx.x;
    const int wid  = t >> 6, lane = t & 63;
    const int wr   = wid >> 2, wc = wid & 3;     // 2 x 4 wave grid
    const int fr   = lane & 15, fq = lane >> 4;
    const int m0   = blockIdx.y * BM, n0 = blockIdx.x * BN;
    const int z    = blockIdx.z;

    const unsigned short* gA0 = g.A0;
    long zA = (long)z * g.batchA;
    if (g.zsplit && z >= g.zsplit) { gA0 = g.A0b; zA = (long)(z - g.zsplit) * g.batchA; }
    const long zB = (long)z * g.batchB;

    // staging geometry: per 64-row round, thread covers row = wid*8+(lane>>3),
    // 16B slot (lane&7); source pre-inverse-swizzled within the 128B row.
    const int srow  = wid * 8 + (lane >> 3);
    const int sgcol = ((lane & 7) ^ (lane >> 3)) * 8;

    f32x4 acc[8][4];
#pragma unroll
    for (int m = 0; m < 8; ++m)
#pragma unroll
        for (int n = 0; n < 4; ++n) acc[m][n] = (f32x4)0.f;

    const int nt = g.K / BK;   // total K-tiles (>= 12 for all uses)

    // staging cursor: group sg (2 loads each); tile sg>>2, part sg&3
    // parts: 0 = B rows 0-127, 1 = B rows 128-255, 2 = A rows 0-127, 3 = A 128-255
    int  sg  = 0;
    long sk0 = 0;
    const unsigned short* sA = gA0 + zA + (long)m0 * g.lda;
    const unsigned short* sB = g.B0 + zB + (long)n0 * g.ldb;

    auto STAGE_GROUP = [&]() {
        if (sg < 4 * nt) {
            const int u  = (sg >> 2) & 1;
            const int gp = sg & 3;
            if (gp < 2) {
                char* lb = (char*)&Bs[u][0] + wid * 1024 + gp * 16384;
                const unsigned short* pb = sB + sk0 + sgcol;
                async16(pb + (long)(srow + gp * 128     ) * g.ldb, lb);
                async16(pb + (long)(srow + gp * 128 + 64) * g.ldb, lb + 8192);
            } else {
                const int ap = gp - 2;
                char* la = (char*)&As[u][0] + wid * 1024 + ap * 16384;
                const unsigned short* pa = sA + sk0 + sgcol;
                async16(pa + (long)(srow + ap * 128     ) * g.lda, la);
                async16(pa + (long)(srow + ap * 128 + 64) * g.lda, la + 8192);
            }
            ++sg;
            if ((sg & 3) == 0) sk0 += BK;
        }
    };

    // prologue: 6 groups ahead (tile0 fully, tile1 B-halves); publish tile0
    STAGE_GROUP(); STAGE_GROUP(); STAGE_GROUP();
    STAGE_GROUP(); STAGE_GROUP(); STAGE_GROUP();
    asm volatile("s_waitcnt vmcnt(4)" ::: "memory");
    __builtin_amdgcn_sched_barrier(0);
    __builtin_amdgcn_s_barrier();
    __builtin_amdgcn_sched_barrier(0);

    bf16x8 fA[4][2], fB[4][2];

    for (int tt = 0; tt < nt; ++tt) {
        const unsigned short* Ab = &As[tt & 1][0];
        const unsigned short* Bb = &Bs[tt & 1][0];

        auto LDA4 = [&](int mbase) {
#pragma unroll
            for (int mi = 0; mi < 4; ++mi) {
                const int rr = wr * 128 + (mbase + mi) * 16 + fr;
                fA[mi][0] = *(const bf16x8*)&Ab[rr * 64 + ((fq    ) ^ (rr & 7)) * 8];
                fA[mi][1] = *(const bf16x8*)&Ab[rr * 64 + ((fq + 4) ^ (rr & 7)) * 8];
            }
        };
        auto LDB2 = [&](int nbase) {
#pragma unroll
            for (int ni = 0; ni < 2; ++ni) {
                const int rr = wc * 64 + (nbase + ni) * 16 + fr;
                fB[nbase + ni][0] = *(const bf16x8*)&Bb[rr * 64 + ((fq    ) ^ (rr & 7)) * 8];
                fB[nbase + ni][1] = *(const bf16x8*)&Bb[rr * 64 + ((fq + 4) ^ (rr & 7)) * 8];
            }
        };
        auto MFMA16 = [&](int mq, int nq) {
            __builtin_amdgcn_s_setprio(1);
#pragma unroll
            for (int mi = 0; mi < 4; ++mi)
#pragma unroll
                for (int ni = 0; ni < 2; ++ni)
#pragma unroll
                    for (int ks = 0; ks < 2; ++ks)
                        acc[mq * 4 + mi][nq * 2 + ni] =
                            __builtin_amdgcn_mfma_f32_16x16x32_bf16(
                                fA[mi][ks], fB[nq * 2 + ni][ks],
                                acc[mq * 4 + mi][nq * 2 + ni], 0, 0, 0);
            __builtin_amdgcn_s_setprio(0);
        };
        auto BAR = [&]() {
            __builtin_amdgcn_sched_barrier(0);
            __builtin_amdgcn_s_barrier();
            __builtin_amdgcn_sched_barrier(0);
        };
        auto LGKM0 = [&]() {
            asm volatile("s_waitcnt lgkmcnt(0)" ::: "memory");
            __builtin_amdgcn_sched_barrier(0);
        };

        // phase 0: read A[0-3]+B[0-1]; stage (tt+1, A rows 0-127); Q(0,0)
        LDA4(0); LDB2(0);
        STAGE_GROUP();
        BAR(); LGKM0();
        MFMA16(0, 0);
        BAR();

        // phase 1: read B[2-3]; stage (tt+1, A rows 128-255); Q(0,1)
        LDB2(2);
        STAGE_GROUP();
        BAR(); LGKM0();
        MFMA16(0, 1);
        BAR();

        // phase 2: read A[4-7]; stage (tt+2, B rows 0-127); Q(1,0)
        LDA4(4);
        STAGE_GROUP();
        BAR(); LGKM0();
        MFMA16(1, 0);
        BAR();

        // phase 3: stage (tt+2, B rows 128-255); Q(1,1); counted vmcnt
        STAGE_GROUP();
        BAR();
        MFMA16(1, 1);
        if (tt >= nt - 2) {
            asm volatile("s_waitcnt vmcnt(0)" ::: "memory");
        } else {
            asm volatile("s_waitcnt vmcnt(4)" ::: "memory");
        }
        BAR();
    }

    // ---- epilogue: C/D layout col = lane&15, row = (lane>>4)*4 + j ----
#pragma unroll
    for (int m = 0; m < 8; ++m) {
        const int gr0 = m0 + wr * 128 + m * 16 + fq * 4;
#pragma unroll
        for (int n = 0; n < 4; ++n) {
            const int gc = n0 + wc * 64 + n * 16 + fr;
            if (EPI == 0) {
                float* Cf = (float*)Cp0 + (long)z * batchC;
#pragma unroll
                for (int j = 0; j < 4; ++j)
                    Cf[(long)(gr0 + j) * ldc + gc] = g.alpha * acc[m][n][j];
            } else if (EPI == 3) {
                unsigned short* H = (unsigned short*)Cp0;
#pragma unroll
                for (int j = 0; j < 4; ++j)
                    H[(long)(gr0 + j) * ldc + gc] = f2bf(acc[m][n][j]);
            } else {
                unsigned short* Vt = (unsigned short*)Cp0;
                ushort4 p;
                p.x = f2bf(acc[m][n][0]); p.y = f2bf(acc[m][n][1]);
                p.z = f2bf(acc[m][n][2]); p.w = f2bf(acc[m][n][3]);
                const long idx = ((long)(gr0 >> 11) * 768 + gc) * 2048 + (gr0 & 2047);
                *(ushort4*)&Vt[idx] = p;
            }
        }
    }
}

// --------------------------- conversion: f32 -> bf16 plane -----------------
__global__ __launch_bounds__(256) void cast_bf16(
    const float* __restrict__ in, unsigned short* __restrict__ outp, int n8)
{
    const int i = blockIdx.x * 256 + threadIdx.x;
    if (i >= n8) return;
    const float4 a = ((const float4*)in)[i * 2];
    const float4 b = ((const float4*)in)[i * 2 + 1];
    ushort4 h0, h1;
    h0.x = f2bf(a.x); h0.y = f2bf(a.y); h0.z = f2bf(a.z); h0.w = f2bf(a.w);
    h1.x = f2bf(b.x); h1.y = f2bf(b.y); h1.z = f2bf(b.z); h1.w = f2bf(b.w);
    ((ushort4*)outp)[i * 2]     = h0;
    ((ushort4*)outp)[i * 2 + 1] = h1;
}

// ------------------------------------------------- top-k + softmax ---------
#define ROWN 2048

__device__ __forceinline__ unsigned fkey(float f) {
    unsigned b = __float_as_uint(f);
    return b ^ ((b & 0x80000000u) ? 0xFFFFFFFFu : 0x80000000u);
}

__global__ __launch_bounds__(256) void topk_softmax_rows(
    const float* __restrict__ S, unsigned short* __restrict__ P, int kkeep)
{
    __shared__ float    sv[ROWN];
    __shared__ unsigned hist[256];
    __shared__ unsigned cum[257];
    __shared__ float    red[256];
    __shared__ unsigned sel_prefix;
    __shared__ unsigned sel_kr;

    const float* row = S + (long)blockIdx.x * ROWN;
    unsigned short* prow = P + (long)blockIdx.x * ROWN;
    const int t = threadIdx.x;

#pragma unroll
    for (int r = 0; r < 2; ++r)
        *reinterpret_cast<float4*>(&sv[t * 4 + r * 1024]) =
            *reinterpret_cast<const float4*>(&row[t * 4 + r * 1024]);
    if (t == 0) { sel_prefix = 0u; sel_kr = (unsigned)kkeep; }
    __syncthreads();

    float m = -3.4e38f;
#pragma unroll
    for (int j = 0; j < 8; ++j) m = fmaxf(m, sv[t + 256 * j]);
    red[t] = m;
    __syncthreads();
    for (int s = 128; s > 0; s >>= 1) {
        if (t < s) red[t] = fmaxf(red[t], red[t + s]);
        __syncthreads();
    }
    const float smax = red[0];
    __syncthreads();

    // radix-select, 3 passes (24-bit threshold; superset of true top-k,
    // expected extras ~0.02/row given order-stat gaps >> 2^-15 quantum)
    for (int p = 3; p >= 1; --p) {
        hist[t] = 0u;
        __syncthreads();
        const unsigned pref = sel_prefix;
        const unsigned kr   = sel_kr;
        const int sh = 8 * p;
        const unsigned himask = ~(((1u << sh) << 8) - 1u);
#pragma unroll
        for (int j = 0; j < 8; ++j) {
            const unsigned u = fkey(sv[t + 256 * j]);
            if (((u ^ pref) & himask) == 0u)
                atomicAdd(&hist[(u >> sh) & 255u], 1u);
        }
        __syncthreads();
        cum[t] = hist[t];
        if (t == 0) cum[256] = 0u;
        __syncthreads();
        for (int s = 1; s < 256; s <<= 1) {
            const unsigned add = (t + s < 256) ? cum[t + s] : 0u;
            __syncthreads();
            cum[t] += add;
            __syncthreads();
        }
        if (cum[t] >= kr && cum[t + 1] < kr) {
            sel_prefix = pref | ((unsigned)t << sh);
            sel_kr     = kr - cum[t + 1];
        }
        __syncthreads();
    }
    const unsigned tu = sel_prefix;

    float s = 0.f;
#pragma unroll
    for (int j = 0; j < 8; ++j) {
        const int i   = t + 256 * j;
        const float x = sv[i];
        const float e = (fkey(x) >= tu) ? __expf(x - smax) : 0.f;
        sv[i] = e;
        s += e;
    }
    red[t] = s;
    __syncthreads();
    for (int st = 128; st > 0; st >>= 1) {
        if (t < st) red[t] += red[t + st];
        __syncthreads();
    }
    const float inv = 1.0f / red[0];
    __syncthreads();

#pragma unroll
    for (int r = 0; r < 2; ++r) {
        const float4 v = *reinterpret_cast<const float4*>(&sv[t * 4 + r * 1024]);
        ushort4 o;
        o.x = f2bf(v.x * inv); o.y = f2bf(v.y * inv);
        o.z = f2bf(v.z * inv); o.w = f2bf(v.w * inv);
        *(ushort4*)&prow[t * 4 + r * 1024] = o;
    }
}

// ---------------------------------------------------------------- launch ---
extern "C" void kernel_launch(void* const* d_in, const int* in_sizes, int n_in,
                              void* d_out, int out_size, void* d_ws, size_t ws_size,
                              hipStream_t stream)
{
    const float* x = (const float*)d_in[0];
    const float* W = (const float*)d_in[1];   // [3C, C]
    float* out = (float*)d_out;

    const int B = 8, N = 2048, C = 768;
    const int M = B * N;                      // 16384
    const int kkeep = 1638;

    char* ws = (char*)d_ws;
    // layout (bytes): QKb 50.33M | Vt 25.17M | S 67.11M | Pb1 33.55M | Pb2 33.55M
    unsigned short* QKb = (unsigned short*)(ws);                    // [M,1536]
    unsigned short* Vt  = (unsigned short*)(ws + 50331648);         // [B][C][N]
    float*          S   = (float*)(ws + 75497472);                  // [4,N,N]
    unsigned short* Pb1 = (unsigned short*)(ws + 142606336);
    unsigned short* Pb2 = (unsigned short*)(ws + 176160768);
    // aliases inside the S region (dead before S is first written):
    unsigned short* xb  = (unsigned short*)(ws + 75497472);                // [M,C]
    unsigned short* Wb  = (unsigned short*)(ws + 75497472 + 25165824);     // [3C,C]

    cast_bf16<<<dim3(M * C / 8 / 256), 256, 0, stream>>>(x, xb, M * C / 8);
    cast_bf16<<<dim3(3 * C * C / 8 / 256), 256, 0, stream>>>(W, Wb, 3 * C * C / 8);

    // ---- projQK: [M,768] x [1536,768]^T -> QKb [M,1536] bf16 ----
    {
        GemmArgs pa{};
        pa.lda = C; pa.ldb = C; pa.batchA = 0; pa.batchB = 0;
        pa.K = C; pa.alpha = 1.f; pa.zsplit = 0;
        pa.A0 = xb; pa.B0 = Wb;
        gemm_bf16<3><<<dim3(1536 / BN, M / BM, 1), NTHREADS, 0, stream>>>(
            pa, QKb, 1536, 0);
    }
    // ---- projV -> Vt [B][C][N] ----
    {
        GemmArgs pv{};
        pv.lda = C; pv.ldb = C; pv.batchA = 0; pv.batchB = 0;
        pv.K = C; pv.alpha = 1.f; pv.zsplit = 0;
        pv.A0 = xb; pv.B0 = Wb + (size_t)1536 * C;
        gemm_bf16<2><<<dim3(C / BN, M / BM, 1), NTHREADS, 0, stream>>>(
            pv, Vt, 0, 0);
    }
    // ---- per half: QK^T -> topk/softmax ----
    for (int h = 0; h < 2; ++h) {
        const size_t ho = (size_t)h * 4 * N * 1536;
        GemmArgs qk{};
        qk.lda = 1536; qk.ldb = 1536;
        qk.batchA = (long)N * 1536; qk.batchB = (long)N * 1536; qk.K = C;
        qk.alpha = 1.0f / sqrtf((float)C); qk.zsplit = 0;
        qk.A0 = QKb + ho;          // Q cols 0-767
        qk.B0 = QKb + ho + C;      // K cols 768-1535
        gemm_bf16<0><<<dim3(N / BN, N / BM, 4), NTHREADS, 0, stream>>>(
            qk, S, N, (long)N * N);

        topk_softmax_rows<<<dim3(4 * N), 256, 0, stream>>>(
            S, h == 0 ? Pb1 : Pb2, kkeep);
    }
    // ---- PV: one z=8 launch (z<4 -> Pb1, z>=4 -> Pb2) ----
    {
        GemmArgs pvv{};
        pvv.lda = N; pvv.ldb = N;
        pvv.batchA = (long)N * N; pvv.batchB = (long)C * N; pvv.K = N;
        pvv.alpha = 1.f;
        pvv.A0 = Pb1; pvv.A0b = Pb2; pvv.zsplit = 4;
        pvv.B0 = Vt;
        gemm_bf16<0><<<dim3(C / BN, N / BM, 8), NTHREADS, 0, stream>>>(
            pvv, out, C, (long)N * C);
    }
}

// Round 8
// 289.193 us; speedup vs baseline: 2.2803x; 1.2688x over previous
//
#include <hip/hip_runtime.h>
#include <hip/hip_bf16.h>
#include <math.h>

// SparseAttention: B=8, N=2048, C=768, k=1638.
// Plain-bf16 MFMA pipeline:
//   cast: x->xb, W->Wb (bf16)
//   projQK: QKb [M,1536] = xb @ Wqk^T     (bf16 out)
//   projV:  Vt  [B][C][N] = xb @ Wv^T     (transposed bf16 out)
//   per half: Sb = Q K^T/sqrt(C) (bf16) -> quantized-histogram top-k select
//             + masked softmax -> Pb (bf16)
//   PV: one z=8 launch (Pb1 | Pb2 pointer split), out f32
// GEMM core: unchanged r6/r7 structure (256x256, 8 waves, BK=64, 2 K-tile LDS
// dbuf, XOR-swizzle involution (0 conflicts), 4 phases/K-tile, counted
// vmcnt(4), setprio) — proven correct r4-r7.
// topk v2: barrier-light (5 syncs), register-resident row, 2048-bin linear-
// quantized histogram select (atomic depth ~3 vs ~300 in exponent-radix v1).

#define BM 256
#define BN 256
#define BK 64
#define NTHREADS 512

typedef __attribute__((ext_vector_type(8))) short bf16x8;
typedef __attribute__((ext_vector_type(4))) float f32x4;

__device__ __forceinline__ unsigned short f2bf(float f) {
    unsigned u = __float_as_uint(f);
    unsigned r = u + 0x7FFFu + ((u >> 16) & 1u);   // RN-even
    return (unsigned short)(r >> 16);
}
__device__ __forceinline__ float bf2f(unsigned short h) {
    return __uint_as_float(((unsigned)h) << 16);
}

__device__ __forceinline__ void async16(const void* g, void* l) {
    __builtin_amdgcn_global_load_lds(
        (const __attribute__((address_space(1))) void*)g,
        (__attribute__((address_space(3))) void*)l, 16, 0, 0);
}

struct GemmArgs {
    const unsigned short* A0;
    const unsigned short* B0;
    const unsigned short* A0b;  // alt A base for z >= zsplit (PV second half)
    int zsplit;                 // 0 = off
    int lda, ldb;               // row strides (elements); A=[M,K], B=[N,K] (NT)
    long batchA, batchB;        // per-z element strides
    int K;                      // multiple of 64
    float alpha;
};

// EPI: 0 = f32 store (alpha) | 2 = transposed bf16 V | 3 = plain bf16
//      4 = bf16 store with alpha + z batch (S logits)
template <int EPI>
__global__ __launch_bounds__(NTHREADS) void gemm_bf16(
    GemmArgs g, void* Cp0, int ldc, long batchC)
{
    // 2 K-tile buffers: 2 x (A 32KB + B 32KB) = 128 KB.
    // Row = 64 k-elems = 128 B = 8 x 16B slots; global slot s of row r stored
    // at LDS slot s ^ (r & 7) (involution; r4/r6-proven, 0 bank conflicts).
    __shared__ unsigned short As[2][BM * BK];
    __shared__ unsigned short Bs[2][BM * BK];

    const int t    = threadIdx.x;
    const int wid  = t >> 6, lane = t & 63;
    const int wr   = wid >> 2, wc = wid & 3;     // 2 x 4 wave grid
    const int fr   = lane & 15, fq = lane >> 4;
    const int m0   = blockIdx.y * BM, n0 = blockIdx.x * BN;
    const int z    = blockIdx.z;

    const unsigned short* gA0 = g.A0;
    long zA = (long)z * g.batchA;
    if (g.zsplit && z >= g.zsplit) { gA0 = g.A0b; zA = (long)(z - g.zsplit) * g.batchA; }
    const long zB = (long)z * g.batchB;

    // staging geometry: per 64-row round, thread covers row = wid*8+(lane>>3),
    // 16B slot (lane&7); source pre-inverse-swizzled within the 128B row.
    const int srow  = wid * 8 + (lane >> 3);
    const int sgcol = ((lane & 7) ^ (lane >> 3)) * 8;

    f32x4 acc[8][4];
#pragma unroll
    for (int m = 0; m < 8; ++m)
#pragma unroll
        for (int n = 0; n < 4; ++n) acc[m][n] = (f32x4)0.f;

    const int nt = g.K / BK;   // total K-tiles (>= 12 for all uses)

    // staging cursor: group sg (2 loads each); tile sg>>2, part sg&3
    // parts: 0 = B rows 0-127, 1 = B rows 128-255, 2 = A rows 0-127, 3 = A 128-255
    int  sg  = 0;
    long sk0 = 0;
    const unsigned short* sA = gA0 + zA + (long)m0 * g.lda;
    const unsigned short* sB = g.B0 + zB + (long)n0 * g.ldb;

    auto STAGE_GROUP = [&]() {
        if (sg < 4 * nt) {
            const int u  = (sg >> 2) & 1;
            const int gp = sg & 3;
            if (gp < 2) {
                char* lb = (char*)&Bs[u][0] + wid * 1024 + gp * 16384;
                const unsigned short* pb = sB + sk0 + sgcol;
                async16(pb + (long)(srow + gp * 128     ) * g.ldb, lb);
                async16(pb + (long)(srow + gp * 128 + 64) * g.ldb, lb + 8192);
            } else {
                const int ap = gp - 2;
                char* la = (char*)&As[u][0] + wid * 1024 + ap * 16384;
                const unsigned short* pa = sA + sk0 + sgcol;
                async16(pa + (long)(srow + ap * 128     ) * g.lda, la);
                async16(pa + (long)(srow + ap * 128 + 64) * g.lda, la + 8192);
            }
            ++sg;
            if ((sg & 3) == 0) sk0 += BK;
        }
    };

    // prologue: 6 groups ahead (tile0 fully, tile1 B-halves); publish tile0
    STAGE_GROUP(); STAGE_GROUP(); STAGE_GROUP();
    STAGE_GROUP(); STAGE_GROUP(); STAGE_GROUP();
    asm volatile("s_waitcnt vmcnt(4)" ::: "memory");
    __builtin_amdgcn_sched_barrier(0);
    __builtin_amdgcn_s_barrier();
    __builtin_amdgcn_sched_barrier(0);

    bf16x8 fA[4][2], fB[4][2];

    for (int tt = 0; tt < nt; ++tt) {
        const unsigned short* Ab = &As[tt & 1][0];
        const unsigned short* Bb = &Bs[tt & 1][0];

        auto LDA4 = [&](int mbase) {
#pragma unroll
            for (int mi = 0; mi < 4; ++mi) {
                const int rr = wr * 128 + (mbase + mi) * 16 + fr;
                fA[mi][0] = *(const bf16x8*)&Ab[rr * 64 + ((fq    ) ^ (rr & 7)) * 8];
                fA[mi][1] = *(const bf16x8*)&Ab[rr * 64 + ((fq + 4) ^ (rr & 7)) * 8];
            }
        };
        auto LDB2 = [&](int nbase) {
#pragma unroll
            for (int ni = 0; ni < 2; ++ni) {
                const int rr = wc * 64 + (nbase + ni) * 16 + fr;
                fB[nbase + ni][0] = *(const bf16x8*)&Bb[rr * 64 + ((fq    ) ^ (rr & 7)) * 8];
                fB[nbase + ni][1] = *(const bf16x8*)&Bb[rr * 64 + ((fq + 4) ^ (rr & 7)) * 8];
            }
        };
        auto MFMA16 = [&](int mq, int nq) {
            __builtin_amdgcn_s_setprio(1);
#pragma unroll
            for (int mi = 0; mi < 4; ++mi)
#pragma unroll
                for (int ni = 0; ni < 2; ++ni)
#pragma unroll
                    for (int ks = 0; ks < 2; ++ks)
                        acc[mq * 4 + mi][nq * 2 + ni] =
                            __builtin_amdgcn_mfma_f32_16x16x32_bf16(
                                fA[mi][ks], fB[nq * 2 + ni][ks],
                                acc[mq * 4 + mi][nq * 2 + ni], 0, 0, 0);
            __builtin_amdgcn_s_setprio(0);
        };
        auto BAR = [&]() {
            __builtin_amdgcn_sched_barrier(0);
            __builtin_amdgcn_s_barrier();
            __builtin_amdgcn_sched_barrier(0);
        };
        auto LGKM0 = [&]() {
            asm volatile("s_waitcnt lgkmcnt(0)" ::: "memory");
            __builtin_amdgcn_sched_barrier(0);
        };

        // phase 0: read A[0-3]+B[0-1]; stage (tt+1, A rows 0-127); Q(0,0)
        LDA4(0); LDB2(0);
        STAGE_GROUP();
        BAR(); LGKM0();
        MFMA16(0, 0);
        BAR();

        // phase 1: read B[2-3]; stage (tt+1, A rows 128-255); Q(0,1)
        LDB2(2);
        STAGE_GROUP();
        BAR(); LGKM0();
        MFMA16(0, 1);
        BAR();

        // phase 2: read A[4-7]; stage (tt+2, B rows 0-127); Q(1,0)
        LDA4(4);
        STAGE_GROUP();
        BAR(); LGKM0();
        MFMA16(1, 0);
        BAR();

        // phase 3: stage (tt+2, B rows 128-255); Q(1,1); counted vmcnt
        STAGE_GROUP();
        BAR();
        MFMA16(1, 1);
        if (tt >= nt - 2) {
            asm volatile("s_waitcnt vmcnt(0)" ::: "memory");
        } else {
            asm volatile("s_waitcnt vmcnt(4)" ::: "memory");
        }
        BAR();
    }

    // ---- epilogue: C/D layout col = lane&15, row = (lane>>4)*4 + j ----
#pragma unroll
    for (int m = 0; m < 8; ++m) {
        const int gr0 = m0 + wr * 128 + m * 16 + fq * 4;
#pragma unroll
        for (int n = 0; n < 4; ++n) {
            const int gc = n0 + wc * 64 + n * 16 + fr;
            if (EPI == 0) {
                float* Cf = (float*)Cp0 + (long)z * batchC;
#pragma unroll
                for (int j = 0; j < 4; ++j)
                    Cf[(long)(gr0 + j) * ldc + gc] = g.alpha * acc[m][n][j];
            } else if (EPI == 3) {
                unsigned short* H = (unsigned short*)Cp0;
#pragma unroll
                for (int j = 0; j < 4; ++j)
                    H[(long)(gr0 + j) * ldc + gc] = f2bf(acc[m][n][j]);
            } else if (EPI == 4) {
                unsigned short* H = (unsigned short*)Cp0 + (long)z * batchC;
#pragma unroll
                for (int j = 0; j < 4; ++j)
                    H[(long)(gr0 + j) * ldc + gc] = f2bf(g.alpha * acc[m][n][j]);
            } else {
                unsigned short* Vt = (unsigned short*)Cp0;
                ushort4 p;
                p.x = f2bf(acc[m][n][0]); p.y = f2bf(acc[m][n][1]);
                p.z = f2bf(acc[m][n][2]); p.w = f2bf(acc[m][n][3]);
                const long idx = ((long)(gr0 >> 11) * 768 + gc) * 2048 + (gr0 & 2047);
                *(ushort4*)&Vt[idx] = p;
            }
        }
    }
}

// --------------------------- conversion: f32 -> bf16 plane -----------------
__global__ __launch_bounds__(256) void cast_bf16(
    const float* __restrict__ in, unsigned short* __restrict__ outp, int n8)
{
    const int i = blockIdx.x * 256 + threadIdx.x;
    if (i >= n8) return;
    const float4 a = ((const float4*)in)[i * 2];
    const float4 b = ((const float4*)in)[i * 2 + 1];
    ushort4 h0, h1;
    h0.x = f2bf(a.x); h0.y = f2bf(a.y); h0.z = f2bf(a.z); h0.w = f2bf(a.w);
    h1.x = f2bf(b.x); h1.y = f2bf(b.y); h1.z = f2bf(b.z); h1.w = f2bf(b.w);
    ((ushort4*)outp)[i * 2]     = h0;
    ((ushort4*)outp)[i * 2 + 1] = h1;
}

// ------------------------- top-k + softmax (v2) ----------------------------
// Per row (block of 256 threads): bf16 logits -> registers; wave-shfl max/min;
// monotone linear quantization to [0,2047]; one-pass 2048-bin LDS histogram;
// wave-parallel suffix scan locates the k-th-largest's bin; keep q >= bin
// (superset: <= ~3 boundary ties extra); exp/sum/normalize -> bf16 probs.
#define ROWN 2048

__global__ __launch_bounds__(256) void topk_softmax_rows(
    const unsigned short* __restrict__ Sb, unsigned short* __restrict__ P,
    int kkeep)
{
    __shared__ __align__(16) unsigned hist[2048];
    __shared__ float    redmax[4], redmin[4], ssum[4];
    __shared__ unsigned wsum[4];
    __shared__ unsigned selBin;

    const unsigned short* row = Sb + (long)blockIdx.x * ROWN;
    unsigned short* prow = P + (long)blockIdx.x * ROWN;
    const int t    = threadIdx.x;
    const int lane = t & 63, w = t >> 6;

    // load 8 bf16 -> f32 registers (16 B coalesced per thread)
    float x[8];
    {
        const ushort4 a = ((const ushort4*)row)[t * 2];
        const ushort4 b = ((const ushort4*)row)[t * 2 + 1];
        x[0] = bf2f(a.x); x[1] = bf2f(a.y); x[2] = bf2f(a.z); x[3] = bf2f(a.w);
        x[4] = bf2f(b.x); x[5] = bf2f(b.y); x[6] = bf2f(b.z); x[7] = bf2f(b.w);
    }
    // zero histogram (8 bins/thread, uint4 stores)
    ((uint4*)hist)[t * 2]     = make_uint4(0, 0, 0, 0);
    ((uint4*)hist)[t * 2 + 1] = make_uint4(0, 0, 0, 0);

    // wave-level max/min (barrier-free), then 4-wave combine
    float mx = x[0], mn = x[0];
#pragma unroll
    for (int j = 1; j < 8; ++j) { mx = fmaxf(mx, x[j]); mn = fminf(mn, x[j]); }
#pragma unroll
    for (int off = 32; off >= 1; off >>= 1) {
        mx = fmaxf(mx, __shfl_xor(mx, off, 64));
        mn = fminf(mn, __shfl_xor(mn, off, 64));
    }
    if (lane == 0) { redmax[w] = mx; redmin[w] = mn; }
    __syncthreads();                       // covers hist zero + red stores
    mx = fmaxf(fmaxf(redmax[0], redmax[1]), fmaxf(redmax[2], redmax[3]));
    mn = fminf(fminf(redmin[0], redmin[1]), fminf(redmin[2], redmin[3]));

    // monotone quantization + histogram (atomic depth ~3 for N(0,1) logits)
    const float scale = 2047.0f / fmaxf(mx - mn, 1e-30f);
    int q[8];
#pragma unroll
    for (int j = 0; j < 8; ++j) {
        int v = (int)((x[j] - mn) * scale);
        q[j] = v < 0 ? 0 : (v > 2047 ? 2047 : v);
        atomicAdd(&hist[q[j]], 1u);
    }
    __syncthreads();

    // suffix scan: thread t owns bins [8t, 8t+8)
    const uint4 h0 = ((const uint4*)hist)[t * 2];
    const uint4 h1 = ((const uint4*)hist)[t * 2 + 1];
    const unsigned hv[8] = { h0.x, h0.y, h0.z, h0.w, h1.x, h1.y, h1.z, h1.w };
    unsigned loc = 0;
#pragma unroll
    for (int j = 0; j < 8; ++j) loc += hv[j];
    // inclusive suffix sum over lanes [lane, 63]
    unsigned s = loc;
#pragma unroll
    for (int off = 1; off <= 32; off <<= 1) {
        const unsigned o = __shfl_down(s, off, 64);
        s += (lane + off < 64) ? o : 0u;
    }
    if (lane == 0) wsum[w] = s;            // wave total
    const unsigned texcl = s - loc;        // suffix over (lane, 63]
    __syncthreads();
    unsigned above = texcl;                // bins > 8t+7 within/above
#pragma unroll
    for (int w2 = 0; w2 < 4; ++w2)
        if (w2 > w) above += wsum[w2];
    // walk own bins high->low; crossing S(b)>=k && S(b+1)<k is unique
    {
        unsigned cum = above;
        int hit = -1;
#pragma unroll
        for (int j = 7; j >= 0; --j) {
            const unsigned sp = cum;
            cum += hv[j];
            if (cum >= (unsigned)kkeep && sp < (unsigned)kkeep) hit = 8 * t + j;
        }
        if (hit >= 0) selBin = (unsigned)hit;
    }
    __syncthreads();
    const int bstar = (int)selBin;

    // masked exp + sum (wave reduce + 4-wave combine)
    float e[8];
    float sum = 0.f;
#pragma unroll
    for (int j = 0; j < 8; ++j) {
        e[j] = (q[j] >= bstar) ? __expf(x[j] - mx) : 0.f;
        sum += e[j];
    }
#pragma unroll
    for (int off = 32; off >= 1; off >>= 1)
        sum += __shfl_xor(sum, off, 64);
    if (lane == 0) ssum[w] = sum;
    __syncthreads();
    const float inv = 1.0f / (ssum[0] + ssum[1] + ssum[2] + ssum[3]);

    ushort4 o0, o1;
    o0.x = f2bf(e[0] * inv); o0.y = f2bf(e[1] * inv);
    o0.z = f2bf(e[2] * inv); o0.w = f2bf(e[3] * inv);
    o1.x = f2bf(e[4] * inv); o1.y = f2bf(e[5] * inv);
    o1.z = f2bf(e[6] * inv); o1.w = f2bf(e[7] * inv);
    ((ushort4*)prow)[t * 2]     = o0;
    ((ushort4*)prow)[t * 2 + 1] = o1;
}

// ---------------------------------------------------------------- launch ---
extern "C" void kernel_launch(void* const* d_in, const int* in_sizes, int n_in,
                              void* d_out, int out_size, void* d_ws, size_t ws_size,
                              hipStream_t stream)
{
    const float* x = (const float*)d_in[0];
    const float* W = (const float*)d_in[1];   // [3C, C]
    float* out = (float*)d_out;

    const int B = 8, N = 2048, C = 768;
    const int M = B * N;                      // 16384
    const int kkeep = 1638;

    char* ws = (char*)d_ws;
    // layout (bytes): QKb 50.33M | Vt 25.17M | Sb 33.55M | Pb1 33.55M | Pb2 33.55M
    unsigned short* QKb = (unsigned short*)(ws);                    // [M,1536]
    unsigned short* Vt  = (unsigned short*)(ws + 50331648);         // [B][C][N]
    unsigned short* Sb  = (unsigned short*)(ws + 75497472);         // [4,N,N] bf16
    unsigned short* Pb1 = (unsigned short*)(ws + 109051904);
    unsigned short* Pb2 = (unsigned short*)(ws + 142606336);
    // aliases inside the Sb region (dead before Sb is first written):
    unsigned short* xb  = (unsigned short*)(ws + 75497472);                // [M,C]
    unsigned short* Wb  = (unsigned short*)(ws + 75497472 + 25165824);     // [3C,C]

    cast_bf16<<<dim3(M * C / 8 / 256), 256, 0, stream>>>(x, xb, M * C / 8);
    cast_bf16<<<dim3(3 * C * C / 8 / 256), 256, 0, stream>>>(W, Wb, 3 * C * C / 8);

    // ---- projQK: [M,768] x [1536,768]^T -> QKb [M,1536] bf16 ----
    {
        GemmArgs pa{};
        pa.lda = C; pa.ldb = C; pa.batchA = 0; pa.batchB = 0;
        pa.K = C; pa.alpha = 1.f; pa.zsplit = 0;
        pa.A0 = xb; pa.B0 = Wb;
        gemm_bf16<3><<<dim3(1536 / BN, M / BM, 1), NTHREADS, 0, stream>>>(
            pa, QKb, 1536, 0);
    }
    // ---- projV -> Vt [B][C][N] ----
    {
        GemmArgs pv{};
        pv.lda = C; pv.ldb = C; pv.batchA = 0; pv.batchB = 0;
        pv.K = C; pv.alpha = 1.f; pv.zsplit = 0;
        pv.A0 = xb; pv.B0 = Wb + (size_t)1536 * C;
        gemm_bf16<2><<<dim3(C / BN, M / BM, 1), NTHREADS, 0, stream>>>(
            pv, Vt, 0, 0);
    }
    // ---- per half: QK^T (bf16 logits) -> topk/softmax ----
    for (int h = 0; h < 2; ++h) {
        const size_t ho = (size_t)h * 4 * N * 1536;
        GemmArgs qk{};
        qk.lda = 1536; qk.ldb = 1536;
        qk.batchA = (long)N * 1536; qk.batchB = (long)N * 1536; qk.K = C;
        qk.alpha = 1.0f / sqrtf((float)C); qk.zsplit = 0;
        qk.A0 = QKb + ho;          // Q cols 0-767
        qk.B0 = QKb + ho + C;      // K cols 768-1535
        gemm_bf16<4><<<dim3(N / BN, N / BM, 4), NTHREADS, 0, stream>>>(
            qk, Sb, N, (long)N * N);

        topk_softmax_rows<<<dim3(4 * N), 256, 0, stream>>>(
            Sb, h == 0 ? Pb1 : Pb2, kkeep);
    }
    // ---- PV: one z=8 launch (z<4 -> Pb1, z>=4 -> Pb2) ----
    {
        GemmArgs pvv{};
        pvv.lda = N; pvv.ldb = N;
        pvv.batchA = (long)N * N; pvv.batchB = (long)C * N; pvv.K = N;
        pvv.alpha = 1.f;
        pvv.A0 = Pb1; pvv.A0b = Pb2; pvv.zsplit = 4;
        pvv.B0 = Vt;
        gemm_bf16<0><<<dim3(C / BN, N / BM, 8), NTHREADS, 0, stream>>>(
            pvv, out, C, (long)N * C);
    }
}

// Round 9
// 267.830 us; speedup vs baseline: 2.4622x; 1.0798x over previous
//
#include <hip/hip_runtime.h>
#include <hip/hip_bf16.h>
#include <math.h>

// SparseAttention: B=8, N=2048, C=768, k=1638.
// Plain-bf16 MFMA pipeline:
//   cast: x->xb, W->Wb (bf16)
//   proj (one launch): cols<1536 -> QKb [M,1536]; cols>=1536 -> Vt [B][C][N]
//   QK^T (one z=8 launch): Sb = Q K^T/sqrt(C) (bf16, [8,N,N])
//   topk (one launch): 2048-bin quantized-histogram select + softmax -> Pb
//   PV (one z=8 launch): out = Pb @ Vt^T (f32)
// GEMM core v3 (occupancy-first): 128x128 tile, 4 waves (2x2), BK=64,
// 64 KB LDS double-buffer -> 2 blocks/CU (TLP covers barrier drains, m114),
// proven XOR-swizzle LDS rows (0 conflicts), counted vmcnt(8) 1-tile
// lookahead, bijective XCD block swizzle (T1) for L2 locality.

#define BM 128
#define BN 128
#define BK 64

typedef __attribute__((ext_vector_type(8))) short bf16x8;
typedef __attribute__((ext_vector_type(4))) float f32x4;

__device__ __forceinline__ unsigned short f2bf(float f) {
    unsigned u = __float_as_uint(f);
    unsigned r = u + 0x7FFFu + ((u >> 16) & 1u);   // RN-even
    return (unsigned short)(r >> 16);
}
__device__ __forceinline__ float bf2f(unsigned short h) {
    return __uint_as_float(((unsigned)h) << 16);
}

__device__ __forceinline__ void async16(const void* g, void* l) {
    __builtin_amdgcn_global_load_lds(
        (const __attribute__((address_space(1))) void*)g,
        (__attribute__((address_space(3))) void*)l, 16, 0, 0);
}

struct GemmArgs {
    const unsigned short* A0;
    const unsigned short* B0;
    int lda, ldb;        // row strides (elements); A=[M,K], B=[N,K] (NT)
    long batchA, batchB; // per-z element strides
    int K;               // multiple of 64
    float alpha;
};

// EPI: 0 = f32 store (alpha, z-batched) | 4 = bf16+alpha (z-batched)
//      5 = proj merged: n0<1536 -> QKb bf16 (Cp0, ldc); else -> Vt (Cp1)
template <int EPI>
__global__ __launch_bounds__(256) void gemm_bf16(
    GemmArgs g, void* Cp0, void* Cp1, int ldc, long batchC)
{
    // double buffer: 2 x (A 16KB + B 16KB) = 64 KB -> 2 blocks/CU.
    // Row = 64 k-elems = 128 B = 8 x 16B slots; global slot s of row r stored
    // at LDS slot s ^ (r & 7) (involution; r4-r8 proven, 0 bank conflicts).
    __shared__ unsigned short As[2][BM * BK];
    __shared__ unsigned short Bs[2][BN * BK];

    // bijective XCD swizzle (all launches have nwg % 8 == 0): contiguous
    // logical block ids land on one XCD -> shared panels hit its L2.
    const int nx  = gridDim.x, ny = gridDim.y;
    const int nwg = nx * ny * gridDim.z;
    const int flat = blockIdx.x + nx * (blockIdx.y + ny * blockIdx.z);
    const int lid  = (flat & 7) * (nwg >> 3) + (flat >> 3);
    const int bx   = lid % nx;
    const int byz  = lid / nx;
    const int by   = byz % ny;
    const int bz   = byz / ny;

    const int t    = threadIdx.x;
    const int wid  = t >> 6, lane = t & 63;
    const int wr   = wid >> 1, wc = wid & 1;     // 2 x 2 wave grid
    const int fr   = lane & 15, fq = lane >> 4;
    const int m0   = by * BM, n0 = bx * BN;

    const unsigned short* Ab0 = g.A0 + (long)bz * g.batchA + (long)m0 * g.lda;
    const unsigned short* Bb0 = g.B0 + (long)bz * g.batchB + (long)n0 * g.ldb;

    // staging: instr i covers rows i*32 + (t>>3), 16B slot (t&7);
    // source slot pre-inverse-swizzled by ^(row&7) = ^((t>>3)&7).
    const int srow = t >> 3;                         // 0..31
    const int sgc  = ((t & 7) ^ (srow & 7)) * 8;     // global k-elem offset

    f32x4 acc[4][4];
#pragma unroll
    for (int m = 0; m < 4; ++m)
#pragma unroll
        for (int n = 0; n < 4; ++n) acc[m][n] = (f32x4)0.f;

    const int nt = g.K / BK;

    auto STAGE = [&](int kt, int u) {
        const long ko = (long)kt * BK + sgc;
#pragma unroll
        for (int i = 0; i < 4; ++i) {
            async16(Ab0 + (long)(i * 32 + srow) * g.lda + ko,
                    (char*)&As[u][0] + i * 4096 + wid * 1024);
            async16(Bb0 + (long)(i * 32 + srow) * g.ldb + ko,
                    (char*)&Bs[u][0] + i * 4096 + wid * 1024);
        }
    };

    STAGE(0, 0);

    for (int tt = 0; tt < nt; ++tt) {
        const int cur = tt & 1;
        if (tt + 1 < nt) {
            STAGE(tt + 1, cur ^ 1);   // 8 loads in flight across the barrier
            asm volatile("s_waitcnt vmcnt(8)" ::: "memory");  // tile tt landed
        } else {
            asm volatile("s_waitcnt vmcnt(0)" ::: "memory");
        }
        __builtin_amdgcn_sched_barrier(0);
        __builtin_amdgcn_s_barrier();
        __builtin_amdgcn_sched_barrier(0);

        const unsigned short* Ab = &As[cur][0];
        const unsigned short* Bb = &Bs[cur][0];
        bf16x8 fA[4][2], fB[4][2];
#pragma unroll
        for (int m = 0; m < 4; ++m) {
            const int rr = wr * 64 + m * 16 + fr;
#pragma unroll
            for (int ks = 0; ks < 2; ++ks)
                fA[m][ks] = *(const bf16x8*)&Ab[rr * 64 + ((ks * 4 + fq) ^ (rr & 7)) * 8];
        }
#pragma unroll
        for (int n = 0; n < 4; ++n) {
            const int rr = wc * 64 + n * 16 + fr;
#pragma unroll
            for (int ks = 0; ks < 2; ++ks)
                fB[n][ks] = *(const bf16x8*)&Bb[rr * 64 + ((ks * 4 + fq) ^ (rr & 7)) * 8];
        }
        __builtin_amdgcn_s_setprio(1);
#pragma unroll
        for (int m = 0; m < 4; ++m)
#pragma unroll
            for (int n = 0; n < 4; ++n)
#pragma unroll
                for (int ks = 0; ks < 2; ++ks)
                    acc[m][n] = __builtin_amdgcn_mfma_f32_16x16x32_bf16(
                        fA[m][ks], fB[n][ks], acc[m][n], 0, 0, 0);
        __builtin_amdgcn_s_setprio(0);
        __builtin_amdgcn_sched_barrier(0);
        __builtin_amdgcn_s_barrier();      // buf[cur] free for restage
        __builtin_amdgcn_sched_barrier(0);
    }

    // ---- epilogue: C/D layout col = lane&15, row = (lane>>4)*4 + j ----
#pragma unroll
    for (int m = 0; m < 4; ++m) {
        const int gr0 = m0 + wr * 64 + m * 16 + fq * 4;
#pragma unroll
        for (int n = 0; n < 4; ++n) {
            const int gc = n0 + wc * 64 + n * 16 + fr;
            if (EPI == 0) {
                float* Cf = (float*)Cp0 + (long)bz * batchC;
#pragma unroll
                for (int j = 0; j < 4; ++j)
                    Cf[(long)(gr0 + j) * ldc + gc] = g.alpha * acc[m][n][j];
            } else if (EPI == 4) {
                unsigned short* H = (unsigned short*)Cp0 + (long)bz * batchC;
#pragma unroll
                for (int j = 0; j < 4; ++j)
                    H[(long)(gr0 + j) * ldc + gc] = f2bf(g.alpha * acc[m][n][j]);
            } else {  // EPI == 5, block-uniform branch (BN=128 divides 1536)
                if (n0 < 1536) {
                    unsigned short* H = (unsigned short*)Cp0;
#pragma unroll
                    for (int j = 0; j < 4; ++j)
                        H[(long)(gr0 + j) * ldc + gc] = f2bf(acc[m][n][j]);
                } else {
                    unsigned short* Vt = (unsigned short*)Cp1;
                    ushort4 p;
                    p.x = f2bf(acc[m][n][0]); p.y = f2bf(acc[m][n][1]);
                    p.z = f2bf(acc[m][n][2]); p.w = f2bf(acc[m][n][3]);
                    const long idx =
                        ((long)(gr0 >> 11) * 768 + (gc - 1536)) * 2048 + (gr0 & 2047);
                    *(ushort4*)&Vt[idx] = p;
                }
            }
        }
    }
}

// --------------------------- conversion: f32 -> bf16 plane -----------------
__global__ __launch_bounds__(256) void cast_bf16(
    const float* __restrict__ in, unsigned short* __restrict__ outp, int n8)
{
    const int i = blockIdx.x * 256 + threadIdx.x;
    if (i >= n8) return;
    const float4 a = ((const float4*)in)[i * 2];
    const float4 b = ((const float4*)in)[i * 2 + 1];
    ushort4 h0, h1;
    h0.x = f2bf(a.x); h0.y = f2bf(a.y); h0.z = f2bf(a.z); h0.w = f2bf(a.w);
    h1.x = f2bf(b.x); h1.y = f2bf(b.y); h1.z = f2bf(b.z); h1.w = f2bf(b.w);
    ((ushort4*)outp)[i * 2]     = h0;
    ((ushort4*)outp)[i * 2 + 1] = h1;
}

// ------------------------- top-k + softmax (v2) ----------------------------
#define ROWN 2048

__global__ __launch_bounds__(256) void topk_softmax_rows(
    const unsigned short* __restrict__ Sb, unsigned short* __restrict__ P,
    int kkeep)
{
    __shared__ __align__(16) unsigned hist[2048];
    __shared__ float    redmax[4], redmin[4], ssum[4];
    __shared__ unsigned wsum[4];
    __shared__ unsigned selBin;

    const unsigned short* row = Sb + (long)blockIdx.x * ROWN;
    unsigned short* prow = P + (long)blockIdx.x * ROWN;
    const int t    = threadIdx.x;
    const int lane = t & 63, w = t >> 6;

    float x[8];
    {
        const ushort4 a = ((const ushort4*)row)[t * 2];
        const ushort4 b = ((const ushort4*)row)[t * 2 + 1];
        x[0] = bf2f(a.x); x[1] = bf2f(a.y); x[2] = bf2f(a.z); x[3] = bf2f(a.w);
        x[4] = bf2f(b.x); x[5] = bf2f(b.y); x[6] = bf2f(b.z); x[7] = bf2f(b.w);
    }
    ((uint4*)hist)[t * 2]     = make_uint4(0, 0, 0, 0);
    ((uint4*)hist)[t * 2 + 1] = make_uint4(0, 0, 0, 0);

    float mx = x[0], mn = x[0];
#pragma unroll
    for (int j = 1; j < 8; ++j) { mx = fmaxf(mx, x[j]); mn = fminf(mn, x[j]); }
#pragma unroll
    for (int off = 32; off >= 1; off >>= 1) {
        mx = fmaxf(mx, __shfl_xor(mx, off, 64));
        mn = fminf(mn, __shfl_xor(mn, off, 64));
    }
    if (lane == 0) { redmax[w] = mx; redmin[w] = mn; }
    __syncthreads();
    mx = fmaxf(fmaxf(redmax[0], redmax[1]), fmaxf(redmax[2], redmax[3]));
    mn = fminf(fminf(redmin[0], redmin[1]), fminf(redmin[2], redmin[3]));

    const float scale = 2047.0f / fmaxf(mx - mn, 1e-30f);
    int q[8];
#pragma unroll
    for (int j = 0; j < 8; ++j) {
        int v = (int)((x[j] - mn) * scale);
        q[j] = v < 0 ? 0 : (v > 2047 ? 2047 : v);
        atomicAdd(&hist[q[j]], 1u);
    }
    __syncthreads();

    const uint4 h0 = ((const uint4*)hist)[t * 2];
    const uint4 h1 = ((const uint4*)hist)[t * 2 + 1];
    const unsigned hv[8] = { h0.x, h0.y, h0.z, h0.w, h1.x, h1.y, h1.z, h1.w };
    unsigned loc = 0;
#pragma unroll
    for (int j = 0; j < 8; ++j) loc += hv[j];
    unsigned s = loc;
#pragma unroll
    for (int off = 1; off <= 32; off <<= 1) {
        const unsigned o = __shfl_down(s, off, 64);
        s += (lane + off < 64) ? o : 0u;
    }
    if (lane == 0) wsum[w] = s;
    const unsigned texcl = s - loc;
    __syncthreads();
    unsigned above = texcl;
#pragma unroll
    for (int w2 = 0; w2 < 4; ++w2)
        if (w2 > w) above += wsum[w2];
    {
        unsigned cum = above;
        int hit = -1;
#pragma unroll
        for (int j = 7; j >= 0; --j) {
            const unsigned sp = cum;
            cum += hv[j];
            if (cum >= (unsigned)kkeep && sp < (unsigned)kkeep) hit = 8 * t + j;
        }
        if (hit >= 0) selBin = (unsigned)hit;
    }
    __syncthreads();
    const int bstar = (int)selBin;

    float e[8];
    float sum = 0.f;
#pragma unroll
    for (int j = 0; j < 8; ++j) {
        e[j] = (q[j] >= bstar) ? __expf(x[j] - mx) : 0.f;
        sum += e[j];
    }
#pragma unroll
    for (int off = 32; off >= 1; off >>= 1)
        sum += __shfl_xor(sum, off, 64);
    if (lane == 0) ssum[w] = sum;
    __syncthreads();
    const float inv = 1.0f / (ssum[0] + ssum[1] + ssum[2] + ssum[3]);

    ushort4 o0, o1;
    o0.x = f2bf(e[0] * inv); o0.y = f2bf(e[1] * inv);
    o0.z = f2bf(e[2] * inv); o0.w = f2bf(e[3] * inv);
    o1.x = f2bf(e[4] * inv); o1.y = f2bf(e[5] * inv);
    o1.z = f2bf(e[6] * inv); o1.w = f2bf(e[7] * inv);
    ((ushort4*)prow)[t * 2]     = o0;
    ((ushort4*)prow)[t * 2 + 1] = o1;
}

// ---------------------------------------------------------------- launch ---
extern "C" void kernel_launch(void* const* d_in, const int* in_sizes, int n_in,
                              void* d_out, int out_size, void* d_ws, size_t ws_size,
                              hipStream_t stream)
{
    const float* x = (const float*)d_in[0];
    const float* W = (const float*)d_in[1];   // [3C, C]
    float* out = (float*)d_out;

    const int B = 8, N = 2048, C = 768;
    const int M = B * N;                      // 16384
    const int kkeep = 1638;

    char* ws = (char*)d_ws;
    // layout (bytes): QKb 50.33M | Vt 25.17M | Sb 67.11M | Pb 67.11M  (209.7M)
    unsigned short* QKb = (unsigned short*)(ws);                    // [M,1536]
    unsigned short* Vt  = (unsigned short*)(ws + 50331648);         // [B][C][N]
    unsigned short* Sb  = (unsigned short*)(ws + 75497472);         // [8,N,N] bf16
    unsigned short* Pb  = (unsigned short*)(ws + 142606336);        // [8,N,N] bf16
    // aliases inside the Sb region (dead before Sb is first written):
    unsigned short* xb  = (unsigned short*)(ws + 75497472);                // [M,C]
    unsigned short* Wb  = (unsigned short*)(ws + 100663296);               // [3C,C]

    cast_bf16<<<dim3(M * C / 8 / 256), 256, 0, stream>>>(x, xb, M * C / 8);
    cast_bf16<<<dim3(3 * C * C / 8 / 256), 256, 0, stream>>>(W, Wb, 3 * C * C / 8);

    // ---- proj (merged QK + V): [M,768] x [2304,768]^T, grid (18,128) ----
    {
        GemmArgs pa{};
        pa.A0 = xb; pa.B0 = Wb;
        pa.lda = C; pa.ldb = C; pa.batchA = 0; pa.batchB = 0;
        pa.K = C; pa.alpha = 1.f;
        gemm_bf16<5><<<dim3(2304 / BN, M / BM, 1), 256, 0, stream>>>(
            pa, QKb, Vt, 1536, 0);
    }
    // ---- QK^T: one z=8 launch -> Sb bf16 logits ----
    {
        GemmArgs qk{};
        qk.A0 = QKb; qk.B0 = QKb + C;
        qk.lda = 1536; qk.ldb = 1536;
        qk.batchA = (long)N * 1536; qk.batchB = (long)N * 1536;
        qk.K = C; qk.alpha = 1.0f / sqrtf((float)C);
        gemm_bf16<4><<<dim3(N / BN, N / BM, 8), 256, 0, stream>>>(
            qk, Sb, nullptr, N, (long)N * N);
    }
    // ---- topk + softmax: all 16384 rows ----
    topk_softmax_rows<<<dim3(B * N), 256, 0, stream>>>(Sb, Pb, kkeep);

    // ---- PV: one z=8 launch -> out f32 ----
    {
        GemmArgs pv{};
        pv.A0 = Pb; pv.B0 = Vt;
        pv.lda = N; pv.ldb = N;
        pv.batchA = (long)N * N; pv.batchB = (long)C * N;
        pv.K = N; pv.alpha = 1.f;
        gemm_bf16<0><<<dim3(C / BN, N / BM, 8), 256, 0, stream>>>(
            pv, out, nullptr, C, (long)N * C);
    }
}

// Round 11
// 243.749 us; speedup vs baseline: 2.7055x; 1.0988x over previous
//
#include <hip/hip_runtime.h>
#include <hip/hip_bf16.h>
#include <math.h>

// SparseAttention: B=8, N=2048, C=768, k=1638.
// Plain-bf16 MFMA pipeline:
//   cast: x->xb, W->Wb (bf16)
//   proj (one launch): cols<1536 -> QKb [M,1536]; cols>=1536 -> Vt [B][C][N]
//   QK^T (one z=8 launch): Sb = Q K^T/sqrt(C) (bf16, [8,N,N])
//   topk (one launch): 2048-bin quantized-histogram select + softmax -> Pb
//   PV (one z=8 launch): out = Pb @ Vt^T (f32)
// GEMM core v4.1: 128x128 tile, 4 waves, BK=64, 64 KB LDS dbuf (2 blk/CU),
// XOR-swizzle (0 conflicts), counted vmcnt(8), XCD swizzle; K-loop fully
// unrolled via template<NT>, staging pointers + LDS read offsets hoisted.
// r10 FIX: double-buffer byte stride is 16384 (BM*BK*2B), not 32768 — the
// r10 NaN was odd-tile reads past As/Bs.

#define BM 128
#define BN 128
#define BK 64

typedef __attribute__((ext_vector_type(8))) short bf16x8;
typedef __attribute__((ext_vector_type(4))) float f32x4;

__device__ __forceinline__ unsigned short f2bf(float f) {
    unsigned u = __float_as_uint(f);
    unsigned r = u + 0x7FFFu + ((u >> 16) & 1u);   // RN-even
    return (unsigned short)(r >> 16);
}
__device__ __forceinline__ float bf2f(unsigned short h) {
    return __uint_as_float(((unsigned)h) << 16);
}

__device__ __forceinline__ void async16(const void* g, void* l) {
    __builtin_amdgcn_global_load_lds(
        (const __attribute__((address_space(1))) void*)g,
        (__attribute__((address_space(3))) void*)l, 16, 0, 0);
}

struct GemmArgs {
    const unsigned short* A0;
    const unsigned short* B0;
    int lda, ldb;        // row strides (elements); A=[M,K], B=[N,K] (NT)
    long batchA, batchB; // per-z element strides
    float alpha;
};

// EPI: 0 = f32 store (alpha, z-batched) | 4 = bf16+alpha (z-batched)
//      5 = proj merged: n0<1536 -> QKb bf16 (Cp0, ldc); else -> Vt (Cp1)
// NT: K-tiles (K = NT*64), compile-time for full unroll.
template <int EPI, int NT>
__global__ __launch_bounds__(256) void gemm_bf16(
    GemmArgs g, void* Cp0, void* Cp1, int ldc, long batchC)
{
    // double buffer: 2 x (A 16KB + B 16KB) = 64 KB -> 2 blocks/CU.
    // Row = 64 k-elems = 128 B = 8 x 16B slots; global slot s of row r stored
    // at LDS slot s ^ (r & 7) (involution; r4-r9 proven, 0 bank conflicts).
    __shared__ unsigned short As[2][BM * BK];
    __shared__ unsigned short Bs[2][BN * BK];

    // bijective XCD swizzle (all launches have nwg % 8 == 0)
    const int nx  = gridDim.x, ny = gridDim.y;
    const int nwg = nx * ny * gridDim.z;
    const int flat = blockIdx.x + nx * (blockIdx.y + ny * blockIdx.z);
    const int lid  = (flat & 7) * (nwg >> 3) + (flat >> 3);
    const int bx   = lid % nx;
    const int byz  = lid / nx;
    const int by   = byz % ny;
    const int bz   = byz / ny;

    const int t    = threadIdx.x;
    const int wid  = t >> 6, lane = t & 63;
    const int wr   = wid >> 1, wc = wid & 1;     // 2 x 2 wave grid
    const int fr   = lane & 15, fq = lane >> 4;
    const int m0   = by * BM, n0 = bx * BN;

    const unsigned short* Ab0 = g.A0 + (long)bz * g.batchA + (long)m0 * g.lda;
    const unsigned short* Bb0 = g.B0 + (long)bz * g.batchB + (long)n0 * g.ldb;

    // ---- loop-invariant staging pointers (8, computed once) ----
    const int srow = t >> 3;                         // 0..31
    const int sgc  = ((t & 7) ^ (srow & 7)) * 8;     // global k-elem offset
    const char* pa[4];
    const char* pb[4];
#pragma unroll
    for (int i = 0; i < 4; ++i) {
        pa[i] = (const char*)(Ab0 + (long)(i * 32 + srow) * g.lda + sgc);
        pb[i] = (const char*)(Bb0 + (long)(i * 32 + srow) * g.ldb + sgc);
    }

    // ---- loop-invariant LDS read byte-offsets (16, computed once) ----
    int aoffs[4][2], boffs[4][2];
#pragma unroll
    for (int m = 0; m < 4; ++m) {
        const int ra = wr * 64 + m * 16 + fr;
        const int rb = wc * 64 + m * 16 + fr;
#pragma unroll
        for (int ks = 0; ks < 2; ++ks) {
            aoffs[m][ks] = ra * 128 + (((ks * 4 + fq) ^ (ra & 7)) * 16);
            boffs[m][ks] = rb * 128 + (((ks * 4 + fq) ^ (rb & 7)) * 16);
        }
    }
    const char* AsBase = (const char*)&As[0][0];
    const char* BsBase = (const char*)&Bs[0][0];

    f32x4 acc[4][4];
#pragma unroll
    for (int m = 0; m < 4; ++m)
#pragma unroll
        for (int n = 0; n < 4; ++n) acc[m][n] = (f32x4)0.f;

    const int ldsT = wid * 1024;   // wave base within each 4KB staging round

#define STAGE(kt, u)                                                          \
    {                                                                         \
        _Pragma("unroll")                                                     \
        for (int i = 0; i < 4; ++i) {                                         \
            async16(pa[i] + (kt) * 128,                                       \
                    (char*)&As[(u)][0] + i * 4096 + ldsT);                    \
            async16(pb[i] + (kt) * 128,                                       \
                    (char*)&Bs[(u)][0] + i * 4096 + ldsT);                    \
        }                                                                     \
    }

    STAGE(0, 0);

#pragma unroll
    for (int tt = 0; tt < NT; ++tt) {
        if (tt + 1 < NT) {
            STAGE(tt + 1, (tt + 1) & 1);   // 8 loads in flight across barrier
            asm volatile("s_waitcnt vmcnt(8)" ::: "memory");
        } else {
            asm volatile("s_waitcnt vmcnt(0)" ::: "memory");
        }
        __builtin_amdgcn_sched_barrier(0);
        __builtin_amdgcn_s_barrier();
        __builtin_amdgcn_sched_barrier(0);

        // buffer byte stride = BM*BK*2 = 16384 (r10 bug: was 32768)
        const int bufo = (tt & 1) * 16384;
        bf16x8 fA[4][2], fB[4][2];
#pragma unroll
        for (int m = 0; m < 4; ++m)
#pragma unroll
            for (int ks = 0; ks < 2; ++ks) {
                fA[m][ks] = *(const bf16x8*)(AsBase + bufo + aoffs[m][ks]);
                fB[m][ks] = *(const bf16x8*)(BsBase + bufo + boffs[m][ks]);
            }
        __builtin_amdgcn_s_setprio(1);
#pragma unroll
        for (int m = 0; m < 4; ++m)
#pragma unroll
            for (int n = 0; n < 4; ++n)
#pragma unroll
                for (int ks = 0; ks < 2; ++ks)
                    acc[m][n] = __builtin_amdgcn_mfma_f32_16x16x32_bf16(
                        fA[m][ks], fB[n][ks], acc[m][n], 0, 0, 0);
        __builtin_amdgcn_s_setprio(0);
        __builtin_amdgcn_sched_barrier(0);
        __builtin_amdgcn_s_barrier();      // buf free for restage
        __builtin_amdgcn_sched_barrier(0);
    }
#undef STAGE

    // ---- epilogue: C/D layout col = lane&15, row = (lane>>4)*4 + j ----
#pragma unroll
    for (int m = 0; m < 4; ++m) {
        const int gr0 = m0 + wr * 64 + m * 16 + fq * 4;
#pragma unroll
        for (int n = 0; n < 4; ++n) {
            const int gc = n0 + wc * 64 + n * 16 + fr;
            if (EPI == 0) {
                float* Cf = (float*)Cp0 + (long)bz * batchC;
#pragma unroll
                for (int j = 0; j < 4; ++j)
                    Cf[(long)(gr0 + j) * ldc + gc] = g.alpha * acc[m][n][j];
            } else if (EPI == 4) {
                unsigned short* H = (unsigned short*)Cp0 + (long)bz * batchC;
#pragma unroll
                for (int j = 0; j < 4; ++j)
                    H[(long)(gr0 + j) * ldc + gc] = f2bf(g.alpha * acc[m][n][j]);
            } else {  // EPI == 5, block-uniform branch (BN=128 divides 1536)
                if (n0 < 1536) {
                    unsigned short* H = (unsigned short*)Cp0;
#pragma unroll
                    for (int j = 0; j < 4; ++j)
                        H[(long)(gr0 + j) * ldc + gc] = f2bf(acc[m][n][j]);
                } else {
                    unsigned short* Vt = (unsigned short*)Cp1;
                    ushort4 p;
                    p.x = f2bf(acc[m][n][0]); p.y = f2bf(acc[m][n][1]);
                    p.z = f2bf(acc[m][n][2]); p.w = f2bf(acc[m][n][3]);
                    const long idx =
                        ((long)(gr0 >> 11) * 768 + (gc - 1536)) * 2048 + (gr0 & 2047);
                    *(ushort4*)&Vt[idx] = p;
                }
            }
        }
    }
}

// --------------------------- conversion: f32 -> bf16 plane -----------------
__global__ __launch_bounds__(256) void cast_bf16(
    const float* __restrict__ in, unsigned short* __restrict__ outp, int n8)
{
    const int i = blockIdx.x * 256 + threadIdx.x;
    if (i >= n8) return;
    const float4 a = ((const float4*)in)[i * 2];
    const float4 b = ((const float4*)in)[i * 2 + 1];
    ushort4 h0, h1;
    h0.x = f2bf(a.x); h0.y = f2bf(a.y); h0.z = f2bf(a.z); h0.w = f2bf(a.w);
    h1.x = f2bf(b.x); h1.y = f2bf(b.y); h1.z = f2bf(b.z); h1.w = f2bf(b.w);
    ((ushort4*)outp)[i * 2]     = h0;
    ((ushort4*)outp)[i * 2 + 1] = h1;
}

// ------------------------- top-k + softmax (v2) ----------------------------
#define ROWN 2048

__global__ __launch_bounds__(256) void topk_softmax_rows(
    const unsigned short* __restrict__ Sb, unsigned short* __restrict__ P,
    int kkeep)
{
    __shared__ __align__(16) unsigned hist[2048];
    __shared__ float    redmax[4], redmin[4], ssum[4];
    __shared__ unsigned wsum[4];
    __shared__ unsigned selBin;

    const unsigned short* row = Sb + (long)blockIdx.x * ROWN;
    unsigned short* prow = P + (long)blockIdx.x * ROWN;
    const int t    = threadIdx.x;
    const int lane = t & 63, w = t >> 6;

    float x[8];
    {
        const ushort4 a = ((const ushort4*)row)[t * 2];
        const ushort4 b = ((const ushort4*)row)[t * 2 + 1];
        x[0] = bf2f(a.x); x[1] = bf2f(a.y); x[2] = bf2f(a.z); x[3] = bf2f(a.w);
        x[4] = bf2f(b.x); x[5] = bf2f(b.y); x[6] = bf2f(b.z); x[7] = bf2f(b.w);
    }
    ((uint4*)hist)[t * 2]     = make_uint4(0, 0, 0, 0);
    ((uint4*)hist)[t * 2 + 1] = make_uint4(0, 0, 0, 0);

    float mx = x[0], mn = x[0];
#pragma unroll
    for (int j = 1; j < 8; ++j) { mx = fmaxf(mx, x[j]); mn = fminf(mn, x[j]); }
#pragma unroll
    for (int off = 32; off >= 1; off >>= 1) {
        mx = fmaxf(mx, __shfl_xor(mx, off, 64));
        mn = fminf(mn, __shfl_xor(mn, off, 64));
    }
    if (lane == 0) { redmax[w] = mx; redmin[w] = mn; }
    __syncthreads();
    mx = fmaxf(fmaxf(redmax[0], redmax[1]), fmaxf(redmax[2], redmax[3]));
    mn = fminf(fminf(redmin[0], redmin[1]), fminf(redmin[2], redmin[3]));

    const float scale = 2047.0f / fmaxf(mx - mn, 1e-30f);
    int q[8];
#pragma unroll
    for (int j = 0; j < 8; ++j) {
        int v = (int)((x[j] - mn) * scale);
        q[j] = v < 0 ? 0 : (v > 2047 ? 2047 : v);
        atomicAdd(&hist[q[j]], 1u);
    }
    __syncthreads();

    const uint4 h0 = ((const uint4*)hist)[t * 2];
    const uint4 h1 = ((const uint4*)hist)[t * 2 + 1];
    const unsigned hv[8] = { h0.x, h0.y, h0.z, h0.w, h1.x, h1.y, h1.z, h1.w };
    unsigned loc = 0;
#pragma unroll
    for (int j = 0; j < 8; ++j) loc += hv[j];
    unsigned s = loc;
#pragma unroll
    for (int off = 1; off <= 32; off <<= 1) {
        const unsigned o = __shfl_down(s, off, 64);
        s += (lane + off < 64) ? o : 0u;
    }
    if (lane == 0) wsum[w] = s;
    const unsigned texcl = s - loc;
    __syncthreads();
    unsigned above = texcl;
#pragma unroll
    for (int w2 = 0; w2 < 4; ++w2)
        if (w2 > w) above += wsum[w2];
    {
        unsigned cum = above;
        int hit = -1;
#pragma unroll
        for (int j = 7; j >= 0; --j) {
            const unsigned sp = cum;
            cum += hv[j];
            if (cum >= (unsigned)kkeep && sp < (unsigned)kkeep) hit = 8 * t + j;
        }
        if (hit >= 0) selBin = (unsigned)hit;
    }
    __syncthreads();
    const int bstar = (int)selBin;

    float e[8];
    float sum = 0.f;
#pragma unroll
    for (int j = 0; j < 8; ++j) {
        e[j] = (q[j] >= bstar) ? __expf(x[j] - mx) : 0.f;
        sum += e[j];
    }
#pragma unroll
    for (int off = 32; off >= 1; off >>= 1)
        sum += __shfl_xor(sum, off, 64);
    if (lane == 0) ssum[w] = sum;
    __syncthreads();
    const float inv = 1.0f / (ssum[0] + ssum[1] + ssum[2] + ssum[3]);

    ushort4 o0, o1;
    o0.x = f2bf(e[0] * inv); o0.y = f2bf(e[1] * inv);
    o0.z = f2bf(e[2] * inv); o0.w = f2bf(e[3] * inv);
    o1.x = f2bf(e[4] * inv); o1.y = f2bf(e[5] * inv);
    o1.z = f2bf(e[6] * inv); o1.w = f2bf(e[7] * inv);
    ((ushort4*)prow)[t * 2]     = o0;
    ((ushort4*)prow)[t * 2 + 1] = o1;
}

// ---------------------------------------------------------------- launch ---
extern "C" void kernel_launch(void* const* d_in, const int* in_sizes, int n_in,
                              void* d_out, int out_size, void* d_ws, size_t ws_size,
                              hipStream_t stream)
{
    const float* x = (const float*)d_in[0];
    const float* W = (const float*)d_in[1];   // [3C, C]
    float* out = (float*)d_out;

    const int B = 8, N = 2048, C = 768;
    const int M = B * N;                      // 16384
    const int kkeep = 1638;

    char* ws = (char*)d_ws;
    // layout (bytes): QKb 50.33M | Vt 25.17M | Sb 67.11M | Pb 67.11M  (209.7M)
    unsigned short* QKb = (unsigned short*)(ws);                    // [M,1536]
    unsigned short* Vt  = (unsigned short*)(ws + 50331648);         // [B][C][N]
    unsigned short* Sb  = (unsigned short*)(ws + 75497472);         // [8,N,N] bf16
    unsigned short* Pb  = (unsigned short*)(ws + 142606336);        // [8,N,N] bf16
    // aliases inside the Sb region (dead before Sb is first written):
    unsigned short* xb  = (unsigned short*)(ws + 75497472);                // [M,C]
    unsigned short* Wb  = (unsigned short*)(ws + 100663296);               // [3C,C]

    cast_bf16<<<dim3(M * C / 8 / 256), 256, 0, stream>>>(x, xb, M * C / 8);
    cast_bf16<<<dim3(3 * C * C / 8 / 256), 256, 0, stream>>>(W, Wb, 3 * C * C / 8);

    // ---- proj (merged QK + V): [M,768] x [2304,768]^T, grid (18,128) ----
    {
        GemmArgs pa{};
        pa.A0 = xb; pa.B0 = Wb;
        pa.lda = C; pa.ldb = C; pa.batchA = 0; pa.batchB = 0;
        pa.alpha = 1.f;
        gemm_bf16<5, 12><<<dim3(2304 / BN, M / BM, 1), 256, 0, stream>>>(
            pa, QKb, Vt, 1536, 0);
    }
    // ---- QK^T: one z=8 launch -> Sb bf16 logits ----
    {
        GemmArgs qk{};
        qk.A0 = QKb; qk.B0 = QKb + C;
        qk.lda = 1536; qk.ldb = 1536;
        qk.batchA = (long)N * 1536; qk.batchB = (long)N * 1536;
        qk.alpha = 1.0f / sqrtf((float)C);
        gemm_bf16<4, 12><<<dim3(N / BN, N / BM, 8), 256, 0, stream>>>(
            qk, Sb, nullptr, N, (long)N * N);
    }
    // ---- topk + softmax: all 16384 rows ----
    topk_softmax_rows<<<dim3(B * N), 256, 0, stream>>>(Sb, Pb, kkeep);

    // ---- PV: one z=8 launch -> out f32 ----
    {
        GemmArgs pv{};
        pv.A0 = Pb; pv.B0 = Vt;
        pv.lda = N; pv.ldb = N;
        pv.batchA = (long)N * N; pv.batchB = (long)C * N;
        pv.alpha = 1.f;
        gemm_bf16<0, 32><<<dim3(C / BN, N / BM, 8), 256, 0, stream>>>(
            pv, out, nullptr, C, (long)N * C);
    }
}

// Round 13
// 239.410 us; speedup vs baseline: 2.7545x; 1.0181x over previous
//
#include <hip/hip_runtime.h>
#include <hip/hip_bf16.h>
#include <math.h>

// SparseAttention: B=8, N=2048, C=768, k=1638.
// r13 = r11 (243.7us, proven) + QK^T converted to 256x256 8-phase schedule.
// r12 post-mortem: i8 PV rejected (absmax 1.37e-2; quant error ~3x margin).
// Pipeline:
//   cast: x->xb, W->Wb (bf16)
//   proj (one launch, 128^2 core): QKb [M,1536] bf16 | Vt [B][C][N] bf16
//   QK^T (z=8, NEW 256^2 8-phase core): Sb = Q K^T/sqrt(C) (bf16 [8,N,N])
//   topk: 2048-bin histogram select + softmax -> Pb bf16
//   PV (z=8, 128^2 core): out = Pb @ Vt^T (f32)

#define BM 128
#define BN 128
#define BK 64

typedef __attribute__((ext_vector_type(8))) short bf16x8;
typedef __attribute__((ext_vector_type(4))) float f32x4;

__device__ __forceinline__ unsigned short f2bf(float f) {
    unsigned u = __float_as_uint(f);
    unsigned r = u + 0x7FFFu + ((u >> 16) & 1u);   // RN-even
    return (unsigned short)(r >> 16);
}
__device__ __forceinline__ float bf2f(unsigned short h) {
    return __uint_as_float(((unsigned)h) << 16);
}

__device__ __forceinline__ void async16(const void* g, void* l) {
    __builtin_amdgcn_global_load_lds(
        (const __attribute__((address_space(1))) void*)g,
        (__attribute__((address_space(3))) void*)l, 16, 0, 0);
}

// ======================= 128^2 2-phase core (r11, proven) ==================
struct GemmArgs {
    const unsigned short* A0;
    const unsigned short* B0;
    int lda, ldb;
    long batchA, batchB;
    float alpha;
};

// EPI: 0 = f32 store (alpha, z-batched) | 5 = proj merged QK bf16 / Vt bf16
template <int EPI, int NT>
__global__ __launch_bounds__(256) void gemm_bf16(
    GemmArgs g, void* Cp0, void* Cp1, int ldc, long batchC)
{
    __shared__ unsigned short As[2][BM * BK];
    __shared__ unsigned short Bs[2][BN * BK];

    const int nx  = gridDim.x, ny = gridDim.y;
    const int nwg = nx * ny * gridDim.z;
    const int flat = blockIdx.x + nx * (blockIdx.y + ny * blockIdx.z);
    const int lid  = (flat & 7) * (nwg >> 3) + (flat >> 3);
    const int bx   = lid % nx;
    const int byz  = lid / nx;
    const int by   = byz % ny;
    const int bz   = byz / ny;

    const int t    = threadIdx.x;
    const int wid  = t >> 6, lane = t & 63;
    const int wr   = wid >> 1, wc = wid & 1;
    const int fr   = lane & 15, fq = lane >> 4;
    const int m0   = by * BM, n0 = bx * BN;

    const unsigned short* Ab0 = g.A0 + (long)bz * g.batchA + (long)m0 * g.lda;
    const unsigned short* Bb0 = g.B0 + (long)bz * g.batchB + (long)n0 * g.ldb;

    const int srow = t >> 3;
    const int sgc  = ((t & 7) ^ (srow & 7)) * 8;
    const char* pa[4];
    const char* pb[4];
#pragma unroll
    for (int i = 0; i < 4; ++i) {
        pa[i] = (const char*)(Ab0 + (long)(i * 32 + srow) * g.lda + sgc);
        pb[i] = (const char*)(Bb0 + (long)(i * 32 + srow) * g.ldb + sgc);
    }

    int aoffs[4][2], boffs[4][2];
#pragma unroll
    for (int m = 0; m < 4; ++m) {
        const int ra = wr * 64 + m * 16 + fr;
        const int rb = wc * 64 + m * 16 + fr;
#pragma unroll
        for (int ks = 0; ks < 2; ++ks) {
            aoffs[m][ks] = ra * 128 + (((ks * 4 + fq) ^ (ra & 7)) * 16);
            boffs[m][ks] = rb * 128 + (((ks * 4 + fq) ^ (rb & 7)) * 16);
        }
    }
    const char* AsBase = (const char*)&As[0][0];
    const char* BsBase = (const char*)&Bs[0][0];

    f32x4 acc[4][4];
#pragma unroll
    for (int m = 0; m < 4; ++m)
#pragma unroll
        for (int n = 0; n < 4; ++n) acc[m][n] = (f32x4)0.f;

    const int ldsT = wid * 1024;

#define STAGE(kt, u)                                                          \
    {                                                                         \
        _Pragma("unroll")                                                     \
        for (int i = 0; i < 4; ++i) {                                         \
            async16(pa[i] + (kt) * 128,                                       \
                    (char*)&As[(u)][0] + i * 4096 + ldsT);                    \
            async16(pb[i] + (kt) * 128,                                       \
                    (char*)&Bs[(u)][0] + i * 4096 + ldsT);                    \
        }                                                                     \
    }

    STAGE(0, 0);

#pragma unroll
    for (int tt = 0; tt < NT; ++tt) {
        if (tt + 1 < NT) {
            STAGE(tt + 1, (tt + 1) & 1);
            asm volatile("s_waitcnt vmcnt(8)" ::: "memory");
        } else {
            asm volatile("s_waitcnt vmcnt(0)" ::: "memory");
        }
        __builtin_amdgcn_sched_barrier(0);
        __builtin_amdgcn_s_barrier();
        __builtin_amdgcn_sched_barrier(0);

        const int bufo = (tt & 1) * 16384;   // buffer stride = BM*BK*2B
        bf16x8 fA[4][2], fB[4][2];
#pragma unroll
        for (int m = 0; m < 4; ++m)
#pragma unroll
            for (int ks = 0; ks < 2; ++ks) {
                fA[m][ks] = *(const bf16x8*)(AsBase + bufo + aoffs[m][ks]);
                fB[m][ks] = *(const bf16x8*)(BsBase + bufo + boffs[m][ks]);
            }
        __builtin_amdgcn_s_setprio(1);
#pragma unroll
        for (int m = 0; m < 4; ++m)
#pragma unroll
            for (int n = 0; n < 4; ++n)
#pragma unroll
                for (int ks = 0; ks < 2; ++ks)
                    acc[m][n] = __builtin_amdgcn_mfma_f32_16x16x32_bf16(
                        fA[m][ks], fB[n][ks], acc[m][n], 0, 0, 0);
        __builtin_amdgcn_s_setprio(0);
        __builtin_amdgcn_sched_barrier(0);
        __builtin_amdgcn_s_barrier();
        __builtin_amdgcn_sched_barrier(0);
    }
#undef STAGE

#pragma unroll
    for (int m = 0; m < 4; ++m) {
        const int gr0 = m0 + wr * 64 + m * 16 + fq * 4;
#pragma unroll
        for (int n = 0; n < 4; ++n) {
            const int gc = n0 + wc * 64 + n * 16 + fr;
            if (EPI == 0) {
                float* Cf = (float*)Cp0 + (long)bz * batchC;
#pragma unroll
                for (int j = 0; j < 4; ++j)
                    Cf[(long)(gr0 + j) * ldc + gc] = g.alpha * acc[m][n][j];
            } else {  // EPI == 5 (block-uniform: BN=128 divides 1536)
                if (n0 < 1536) {
                    unsigned short* H = (unsigned short*)Cp0;
#pragma unroll
                    for (int j = 0; j < 4; ++j)
                        H[(long)(gr0 + j) * ldc + gc] = f2bf(acc[m][n][j]);
                } else {
                    unsigned short* Vt = (unsigned short*)Cp1;
                    ushort4 p;
                    p.x = f2bf(acc[m][n][0]); p.y = f2bf(acc[m][n][1]);
                    p.z = f2bf(acc[m][n][2]); p.w = f2bf(acc[m][n][3]);
                    const long idx =
                        ((long)(gr0 >> 11) * 768 + (gc - 1536)) * 2048 + (gr0 & 2047);
                    *(ushort4*)&Vt[idx] = p;
                }
            }
        }
    }
}

// ================== 256^2 8-phase QK^T core (m201-style) ===================
// 8 waves (2Mx4N), per-wave 128x64 out, BK=64, 2 K-tile dbuf (128KB LDS).
// Half-tile staging schedule (hand-verified): ph1: A1(tb); ph3: B0(ta+2);
// ph4: B1+A0(ta+2); ph5: A1(ta+2); ph7: B0(tb+2); ph8: B1+A0(tb+2).
// vmcnt(6) at ph4/ph8 forces exactly the required halves landed (3 halves
// = 6 loads stay in flight). All indices compile-time (full unroll).
template <int NITER>
__global__ __launch_bounds__(512) void gemm_qk8(
    const unsigned short* __restrict__ Aq, const unsigned short* __restrict__ Bk,
    unsigned short* __restrict__ Sb, float alpha)
{
    __shared__ unsigned short As[2][256 * 64];   // 2 x 32KB
    __shared__ unsigned short Bs[2][256 * 64];   // 2 x 32KB

    const int nx  = gridDim.x, ny = gridDim.y;          // (8,8,8)
    const int nwg = nx * ny * gridDim.z;
    const int flat = blockIdx.x + nx * (blockIdx.y + ny * blockIdx.z);
    const int lid  = (flat & 7) * (nwg >> 3) + (flat >> 3);
    const int bx   = lid % nx;
    const int byz  = lid / nx;
    const int by   = byz % ny;
    const int bz   = byz / ny;

    const int t    = threadIdx.x;
    const int wid  = t >> 6, lane = t & 63;
    const int wr   = wid >> 2, wc = wid & 3;            // 2 x 4 waves
    const int fr   = lane & 15, fq = lane >> 4;
    const int m0   = by * 256, n0 = bx * 256;

    const unsigned short* Ab0 = Aq + (long)bz * 2048 * 1536 + (long)m0 * 1536;
    const unsigned short* Bb0 = Bk + (long)bz * 2048 * 1536 + (long)n0 * 1536;

    // staging: srow = t>>3 (0..63), slot = t&7; rounds i cover rows i*64+srow.
    // source slot pre-inverse-swizzled by ^(row&7) = ^(srow&7) (row mod 8 inv).
    const int srow = t >> 3;
    const int sgc  = ((t & 7) ^ (srow & 7)) * 8;
    const char* pa[4];
    const char* pb[4];
#pragma unroll
    for (int i = 0; i < 4; ++i) {
        pa[i] = (const char*)(Ab0 + (long)(i * 64 + srow) * 1536 + sgc);
        pb[i] = (const char*)(Bb0 + (long)(i * 64 + srow) * 1536 + sgc);
    }

    // LDS read addressing: rr&7 == fr&7 (m,n,wr,wc contribute multiples of 8)
    // -> off(m|n, ks) = base + idx*2048 + xo[ks]; 3 registers total.
    const int xo0 = ((fq    ) ^ (fr & 7)) * 16;
    const int xo1 = ((fq + 4) ^ (fr & 7)) * 16;
    const int abase = (wr * 128 + fr) * 128;
    const int bbase = (wc * 64  + fr) * 128;
    const char* AsB = (const char*)&As[0][0];
    const char* BsB = (const char*)&Bs[0][0];
    const int ldsT = wid * 1024;

    f32x4 acc[8][4];
#pragma unroll
    for (int m = 0; m < 8; ++m)
#pragma unroll
        for (int n = 0; n < 4; ++n) acc[m][n] = (f32x4)0.f;

#define SA_(h, kt)                                                            \
    { char* d = (char*)&As[(kt) & 1][0] + (h) * 16384 + ldsT;                 \
      async16(pa[2 * (h)]     + (long)(kt) * 128, d);                         \
      async16(pa[2 * (h) + 1] + (long)(kt) * 128, d + 8192); }
#define SB_(h, kt)                                                            \
    { char* d = (char*)&Bs[(kt) & 1][0] + (h) * 16384 + ldsT;                 \
      async16(pb[2 * (h)]     + (long)(kt) * 128, d);                         \
      async16(pb[2 * (h) + 1] + (long)(kt) * 128, d + 8192); }
#define BARRIER { __builtin_amdgcn_sched_barrier(0);                          \
                  __builtin_amdgcn_s_barrier();                               \
                  __builtin_amdgcn_sched_barrier(0); }
#define LG0 { asm volatile("s_waitcnt lgkmcnt(0)" ::: "memory");              \
              __builtin_amdgcn_sched_barrier(0); }
#define VM6 { asm volatile("s_waitcnt vmcnt(6)" ::: "memory");                \
              __builtin_amdgcn_sched_barrier(0); }
#define VM0 { asm volatile("s_waitcnt vmcnt(0)" ::: "memory");                \
              __builtin_amdgcn_sched_barrier(0); }
#define LDA4_(bp, mq)                                                         \
    _Pragma("unroll") for (int mi = 0; mi < 4; ++mi) {                        \
        fA[mi][0] = *(const bf16x8*)((bp) + abase + ((mq)*4+mi)*2048 + xo0);  \
        fA[mi][1] = *(const bf16x8*)((bp) + abase + ((mq)*4+mi)*2048 + xo1);  \
    }
#define LDB2_(bp, nb)                                                         \
    _Pragma("unroll") for (int ni = 0; ni < 2; ++ni) {                        \
        fB[(nb)+ni][0] = *(const bf16x8*)((bp) + bbase + ((nb)+ni)*2048 + xo0);\
        fB[(nb)+ni][1] = *(const bf16x8*)((bp) + bbase + ((nb)+ni)*2048 + xo1);\
    }
#define MM16_(mq, nq)                                                         \
    __builtin_amdgcn_s_setprio(1);                                            \
    _Pragma("unroll") for (int mi = 0; mi < 4; ++mi)                          \
    _Pragma("unroll") for (int ni = 0; ni < 2; ++ni)                          \
    _Pragma("unroll") for (int ks = 0; ks < 2; ++ks)                          \
        acc[(mq)*4+mi][(nq)*2+ni] = __builtin_amdgcn_mfma_f32_16x16x32_bf16(  \
            fA[mi][ks], fB[(nq)*2+ni][ks], acc[(mq)*4+mi][(nq)*2+ni], 0,0,0); \
    __builtin_amdgcn_s_setprio(0);

    // prologue: tile0 fully + tile1 {B0,B1,A0} = 14 loads; vmcnt(6) forces
    // tile0's 8 landed, leaves tile1's 6 in flight.
    SB_(0, 0); SB_(1, 0); SA_(0, 0); SA_(1, 0);
    SB_(0, 1); SB_(1, 1); SA_(0, 1);
    VM6; BARRIER;

    bf16x8 fA[4][2], fB[4][2];
#pragma unroll
    for (int it = 0; it < NITER; ++it) {
        const int tb = 2 * it + 1;
        const bool last = (it == NITER - 1);
        const char* A0p = AsB;           // even tile -> buf0
        const char* B0p = BsB;
        const char* A1p = AsB + 32768;   // odd tile -> buf1
        const char* B1p = BsB + 32768;

        // ---- phases 1-4: tile 2i (buf0) ----
        LDA4_(A0p, 0); LDB2_(B0p, 0);
        SA_(1, tb);                          // A1 of tile 2i+1 (landed @ph4)
        BARRIER; LG0; MM16_(0, 0); BARRIER;

        LDB2_(B0p, 2);
        BARRIER; LG0; MM16_(0, 1); BARRIER;

        LDA4_(A0p, 1);
        if (!last) SB_(0, tb + 1);           // B0 of tile 2i+2
        BARRIER; LG0; MM16_(1, 0); BARRIER;

        if (!last) { SB_(1, tb + 1); SA_(0, tb + 1); }
        BARRIER;
        MM16_(1, 1);
        if (last) VM0 else VM6;              // tile 2i+1 fully landed
        BARRIER;

        // ---- phases 5-8: tile 2i+1 (buf1) ----
        LDA4_(A1p, 0); LDB2_(B1p, 0);
        if (!last) SA_(1, tb + 1);           // A1 of tile 2i+2
        BARRIER; LG0; MM16_(0, 0); BARRIER;

        LDB2_(B1p, 2);
        BARRIER; LG0; MM16_(0, 1); BARRIER;

        LDA4_(A1p, 1);
        if (!last) SB_(0, tb + 2);           // B0 of tile 2i+3
        BARRIER; LG0; MM16_(1, 0); BARRIER;

        if (!last) { SB_(1, tb + 2); SA_(0, tb + 2); }
        BARRIER;
        MM16_(1, 1);
        if (last) VM0 else VM6;              // tile 2i+2 fully landed
        BARRIER;
    }
#undef SA_
#undef SB_
#undef BARRIER
#undef LG0
#undef VM6
#undef VM0
#undef LDA4_
#undef LDB2_
#undef MM16_

    // ---- epilogue: bf16 + alpha, ldc = 2048 ----
    unsigned short* H = Sb + (long)bz * 2048 * 2048;
#pragma unroll
    for (int m = 0; m < 8; ++m) {
        const int gr0 = m0 + wr * 128 + m * 16 + fq * 4;
#pragma unroll
        for (int n = 0; n < 4; ++n) {
            const int gc = n0 + wc * 64 + n * 16 + fr;
#pragma unroll
            for (int j = 0; j < 4; ++j)
                H[(long)(gr0 + j) * 2048 + gc] = f2bf(alpha * acc[m][n][j]);
        }
    }
}

// --------------------------- conversion: f32 -> bf16 plane -----------------
__global__ __launch_bounds__(256) void cast_bf16(
    const float* __restrict__ in, unsigned short* __restrict__ outp, int n8)
{
    const int i = blockIdx.x * 256 + threadIdx.x;
    if (i >= n8) return;
    const float4 a = ((const float4*)in)[i * 2];
    const float4 b = ((const float4*)in)[i * 2 + 1];
    ushort4 h0, h1;
    h0.x = f2bf(a.x); h0.y = f2bf(a.y); h0.z = f2bf(a.z); h0.w = f2bf(a.w);
    h1.x = f2bf(b.x); h1.y = f2bf(b.y); h1.z = f2bf(b.z); h1.w = f2bf(b.w);
    ((ushort4*)outp)[i * 2]     = h0;
    ((ushort4*)outp)[i * 2 + 1] = h1;
}

// ------------------------- top-k + softmax (v2) ----------------------------
#define ROWN 2048

__global__ __launch_bounds__(256) void topk_softmax_rows(
    const unsigned short* __restrict__ Sb, unsigned short* __restrict__ P,
    int kkeep)
{
    __shared__ __align__(16) unsigned hist[2048];
    __shared__ float    redmax[4], redmin[4], ssum[4];
    __shared__ unsigned wsum[4];
    __shared__ unsigned selBin;

    const unsigned short* row = Sb + (long)blockIdx.x * ROWN;
    unsigned short* prow = P + (long)blockIdx.x * ROWN;
    const int t    = threadIdx.x;
    const int lane = t & 63, w = t >> 6;

    float x[8];
    {
        const ushort4 a = ((const ushort4*)row)[t * 2];
        const ushort4 b = ((const ushort4*)row)[t * 2 + 1];
        x[0] = bf2f(a.x); x[1] = bf2f(a.y); x[2] = bf2f(a.z); x[3] = bf2f(a.w);
        x[4] = bf2f(b.x); x[5] = bf2f(b.y); x[6] = bf2f(b.z); x[7] = bf2f(b.w);
    }
    ((uint4*)hist)[t * 2]     = make_uint4(0, 0, 0, 0);
    ((uint4*)hist)[t * 2 + 1] = make_uint4(0, 0, 0, 0);

    float mx = x[0], mn = x[0];
#pragma unroll
    for (int j = 1; j < 8; ++j) { mx = fmaxf(mx, x[j]); mn = fminf(mn, x[j]); }
#pragma unroll
    for (int off = 32; off >= 1; off >>= 1) {
        mx = fmaxf(mx, __shfl_xor(mx, off, 64));
        mn = fminf(mn, __shfl_xor(mn, off, 64));
    }
    if (lane == 0) { redmax[w] = mx; redmin[w] = mn; }
    __syncthreads();
    mx = fmaxf(fmaxf(redmax[0], redmax[1]), fmaxf(redmax[2], redmax[3]));
    mn = fminf(fminf(redmin[0], redmin[1]), fminf(redmin[2], redmin[3]));

    const float scale = 2047.0f / fmaxf(mx - mn, 1e-30f);
    int q[8];
#pragma unroll
    for (int j = 0; j < 8; ++j) {
        int v = (int)((x[j] - mn) * scale);
        q[j] = v < 0 ? 0 : (v > 2047 ? 2047 : v);
        atomicAdd(&hist[q[j]], 1u);
    }
    __syncthreads();

    const uint4 h0 = ((const uint4*)hist)[t * 2];
    const uint4 h1 = ((const uint4*)hist)[t * 2 + 1];
    const unsigned hv[8] = { h0.x, h0.y, h0.z, h0.w, h1.x, h1.y, h1.z, h1.w };
    unsigned loc = 0;
#pragma unroll
    for (int j = 0; j < 8; ++j) loc += hv[j];
    unsigned s = loc;
#pragma unroll
    for (int off = 1; off <= 32; off <<= 1) {
        const unsigned o = __shfl_down(s, off, 64);
        s += (lane + off < 64) ? o : 0u;
    }
    if (lane == 0) wsum[w] = s;
    const unsigned texcl = s - loc;
    __syncthreads();
    unsigned above = texcl;
#pragma unroll
    for (int w2 = 0; w2 < 4; ++w2)
        if (w2 > w) above += wsum[w2];
    {
        unsigned cum = above;
        int hit = -1;
#pragma unroll
        for (int j = 7; j >= 0; --j) {
            const unsigned sp = cum;
            cum += hv[j];
            if (cum >= (unsigned)kkeep && sp < (unsigned)kkeep) hit = 8 * t + j;
        }
        if (hit >= 0) selBin = (unsigned)hit;
    }
    __syncthreads();
    const int bstar = (int)selBin;

    float e[8];
    float sum = 0.f;
#pragma unroll
    for (int j = 0; j < 8; ++j) {
        e[j] = (q[j] >= bstar) ? __expf(x[j] - mx) : 0.f;
        sum += e[j];
    }
#pragma unroll
    for (int off = 32; off >= 1; off >>= 1)
        sum += __shfl_xor(sum, off, 64);
    if (lane == 0) ssum[w] = sum;
    __syncthreads();
    const float inv = 1.0f / (ssum[0] + ssum[1] + ssum[2] + ssum[3]);

    ushort4 o0, o1;
    o0.x = f2bf(e[0] * inv); o0.y = f2bf(e[1] * inv);
    o0.z = f2bf(e[2] * inv); o0.w = f2bf(e[3] * inv);
    o1.x = f2bf(e[4] * inv); o1.y = f2bf(e[5] * inv);
    o1.z = f2bf(e[6] * inv); o1.w = f2bf(e[7] * inv);
    ((ushort4*)prow)[t * 2]     = o0;
    ((ushort4*)prow)[t * 2 + 1] = o1;
}

// ---------------------------------------------------------------- launch ---
extern "C" void kernel_launch(void* const* d_in, const int* in_sizes, int n_in,
                              void* d_out, int out_size, void* d_ws, size_t ws_size,
                              hipStream_t stream)
{
    const float* x = (const float*)d_in[0];
    const float* W = (const float*)d_in[1];   // [3C, C]
    float* out = (float*)d_out;

    const int B = 8, N = 2048, C = 768;
    const int M = B * N;                      // 16384
    const int kkeep = 1638;

    char* ws = (char*)d_ws;
    // layout (bytes): QKb 50.33M | Vt 25.17M | Sb 67.11M | Pb 67.11M (209.7M)
    unsigned short* QKb = (unsigned short*)(ws);                    // [M,1536]
    unsigned short* Vt  = (unsigned short*)(ws + 50331648);         // [B][C][N]
    unsigned short* Sb  = (unsigned short*)(ws + 75497472);         // [8,N,N]
    unsigned short* Pb  = (unsigned short*)(ws + 142606336);        // [8,N,N]
    // aliases inside the Sb region (dead before Sb is first written):
    unsigned short* xb = (unsigned short*)(ws + 75497472);              // [M,C]
    unsigned short* Wb = (unsigned short*)(ws + 100663296);             // [3C,C]

    cast_bf16<<<dim3(M * C / 8 / 256), 256, 0, stream>>>(x, xb, M * C / 8);
    cast_bf16<<<dim3(3 * C * C / 8 / 256), 256, 0, stream>>>(W, Wb, 3 * C * C / 8);

    // ---- proj (merged QK + V): [M,768] x [2304,768]^T, 128^2 core ----
    {
        GemmArgs pa{};
        pa.A0 = xb; pa.B0 = Wb;
        pa.lda = C; pa.ldb = C; pa.batchA = 0; pa.batchB = 0;
        pa.alpha = 1.f;
        gemm_bf16<5, 12><<<dim3(2304 / BN, M / BM, 1), 256, 0, stream>>>(
            pa, QKb, Vt, 1536, 0);
    }
    // ---- QK^T: 256^2 8-phase core, grid (8,8,8) ----
    gemm_qk8<6><<<dim3(8, 8, 8), 512, 0, stream>>>(
        QKb, QKb + C, Sb, 1.0f / sqrtf((float)C));

    // ---- topk + softmax: all 16384 rows ----
    topk_softmax_rows<<<dim3(B * N), 256, 0, stream>>>(Sb, Pb, kkeep);

    // ---- PV: z=8, 128^2 core -> out f32 ----
    {
        GemmArgs pv{};
        pv.A0 = Pb; pv.B0 = Vt;
        pv.lda = N; pv.ldb = N;
        pv.batchA = (long)N * N; pv.batchB = (long)C * N;
        pv.alpha = 1.f;
        gemm_bf16<0, 32><<<dim3(C / BN, N / BM, 8), 256, 0, stream>>>(
            pv, out, nullptr, C, (long)N * C);
    }
}